// Round 7
// baseline (24594.722 us; speedup 1.0000x reference)
//
#include <hip/hip_runtime.h>
#include <hip/hip_bf16.h>

typedef __attribute__((ext_vector_type(8))) short short8;
typedef __attribute__((ext_vector_type(4))) float f32x4;

__device__ __forceinline__ float gelu_f(float x) {
  return 0.5f * x * (1.0f + erff(x * 0.70710678118654752440f));
}
__device__ __forceinline__ short f2bf(float f) {
  unsigned u = __float_as_uint(f);
  u += 0x7fffu + ((u >> 16) & 1u);
  return (short)(u >> 16);
}
__device__ __forceinline__ float bf2f(short s) {
  return __uint_as_float(((unsigned)(unsigned short)s) << 16);
}
__device__ __forceinline__ void split2(float v, short& h, short& l) {
  h = f2bf(v);
  l = f2bf(v - bf2f(h));
}
__device__ __forceinline__ int swz(int col, int row) {
  return (col & ~63) | ((col & 63) ^ ((row & 7) << 3));
}

__device__ __forceinline__ float block_sum_256(float v, float* sb) {
#pragma unroll
  for (int o = 1; o < 64; o <<= 1) v += __shfl_xor(v, o, 64);
  if ((threadIdx.x & 63) == 0) sb[threadIdx.x >> 6] = v;
  __syncthreads();
  float r = sb[0] + sb[1] + sb[2] + sb[3];
  __syncthreads();
  return r;
}

// ------- weight transpose + convert: fp32 [K][N] -> bf16 hi/lo [N][K] swz --
__global__ __launch_bounds__(256) void convert_w(
    const float* __restrict__ in, short* __restrict__ outh,
    short* __restrict__ outl, int K, int N, int ldn, int group,
    long long gstride, long long in_lstride, long long out_lstride) {
  const float* inl = in + (long long)blockIdx.z * in_lstride;
  short* outhl = outh + (long long)blockIdx.z * out_lstride;
  short* outll = outl + (long long)blockIdx.z * out_lstride;
  const int n = blockIdx.x * 64 + (threadIdx.x & 63);
  const int seg = threadIdx.x >> 6;  // 0..3
  const int k0 = blockIdx.y * 128 + seg * 32;
  if (k0 >= K) return;
  const float* ip = inl + (long long)(n / group) * gstride + (n % group);
  float v[32];
#pragma unroll
  for (int i = 0; i < 32; ++i) v[i] = ip[(long long)(k0 + i) * ldn];
  const long long rowbase = (long long)n * K;
  const int grp = (n & 7) << 3;
#pragma unroll
  for (int j = 0; j < 4; ++j) {
    int k = k0 + j * 8;
    int kk = (k & ~63) | ((k & 63) ^ grp);
    short8 sh, sl;
#pragma unroll
    for (int i = 0; i < 8; ++i) {
      short h, L;
      split2(v[j * 8 + i], h, L);
      sh[i] = h;
      sl[i] = L;
    }
    *(short8*)(outhl + rowbase + kk) = sh;
    *(short8*)(outll + rowbase + kk) = sl;
  }
}

// ---------------- megakernel args ----------------
struct MegaArgs {
  const float *x, *cw, *cb, *cls, *pos;
  const float *bqkv, *bo, *ln1g, *ln1b, *ln2g, *ln2b, *bm1, *bm2;
  const float *Wh1, *bh1, *Wh2, *bh2, *Wh3, *bh3;
  float* out;
  int* arrive;  // 512 slots, 16 ints (64B) apart
  int* go;      // 512 slots, 16 ints apart
  float *tok, *y1, *Pb, *qkvf, *hh1, *hh2;
  short *zh, *zl, *Oh, *Ol, *h1h, *h1l;
  const short *Wqh, *Wql, *Woh, *Wol, *W1h, *W1l, *W2h, *W2l;
};

// Tree grid barrier, contention-free: per-block arrive/go cachelines,
// epoch-numbered (monotonic). Block 0 fans in (256 threads x 2 slots),
// then fans out per-block go flags. Each spin polls a line with a single
// reader and single writer -> no hot-line queuing at the coherence point.
__device__ __forceinline__ void gsync(int* arrive, int* go, int e, int nb) {
  __syncthreads();
  if (blockIdx.x == 0) {
    if (threadIdx.x == 0) {
      __threadfence();
      __hip_atomic_store(&arrive[0], e, __ATOMIC_RELEASE,
                         __HIP_MEMORY_SCOPE_AGENT);
    }
    for (int b = threadIdx.x; b < nb; b += 256) {
      while (__hip_atomic_load(&arrive[b * 16], __ATOMIC_ACQUIRE,
                               __HIP_MEMORY_SCOPE_AGENT) < e)
        __builtin_amdgcn_s_sleep(8);
    }
    __syncthreads();
    if (threadIdx.x == 0) __threadfence();
    __syncthreads();
    for (int b = threadIdx.x; b < nb; b += 256)
      __hip_atomic_store(&go[b * 16], e, __ATOMIC_RELEASE,
                         __HIP_MEMORY_SCOPE_AGENT);
  } else {
    if (threadIdx.x == 0) {
      __threadfence();
      __hip_atomic_store(&arrive[blockIdx.x * 16], e, __ATOMIC_RELEASE,
                         __HIP_MEMORY_SCOPE_AGENT);
      while (__hip_atomic_load(&go[blockIdx.x * 16], __ATOMIC_ACQUIRE,
                               __HIP_MEMORY_SCOPE_AGENT) < e)
        __builtin_amdgcn_s_sleep(8);
      __threadfence();
    }
  }
  __syncthreads();
}

// ---------------- phase bodies (verbatim from round-5 kernels) -------
__device__ void embed_body(const MegaArgs& a, int r, char* smem) {
  float* sb = (float*)smem;
  int b = r / 65, s = r % 65;
  int d = threadIdx.x;
  float val;
  if (s == 0) {
    val = a.cls[d];
  } else {
    int p = s - 1, pi = p >> 3, pj = p & 7;
    const float* xb = a.x + b * 3072 + pi * 4 * 32 + pj * 4;
    const float* w = a.cw + d * 48;
    float acc = a.cb[d];
#pragma unroll
    for (int c = 0; c < 3; ++c)
#pragma unroll
      for (int i = 0; i < 4; ++i)
#pragma unroll
        for (int j = 0; j < 4; ++j)
          acc += xb[c * 1024 + i * 32 + j] * w[c * 16 + i * 4 + j];
    val = acc;
  }
  val += a.pos[s * 256 + d];
  a.tok[r * 256 + d] = val;
  float mean = block_sum_256(val, sb) * (1.0f / 256.0f);
  float dv = val - mean;
  float var = block_sum_256(dv * dv, sb) * (1.0f / 256.0f);
  float z = dv * rsqrtf(var + 1e-5f) * a.ln1g[d] + a.ln1b[d];
  short h, L;
  split2(z, h, L);
  a.zh[r * 256 + swz(d, r)] = h;
  a.zl[r * 256 + swz(d, r)] = L;
}

__device__ void gemm_body(const short* __restrict__ Ah,
                          const short* __restrict__ Al,
                          const short* __restrict__ Bh,
                          const short* __restrict__ Bl, int M, int N, int K,
                          int kchunk, const float* __restrict__ bias,
                          float* __restrict__ out32, float* __restrict__ P,
                          int bx, int by, int bz, char* smem) {
  short* Ash = (short*)smem;
  short* Asl = (short*)(smem + 16384);
  short* Bsh = (short*)(smem + 32768);
  short* Bsl = (short*)(smem + 49152);
  const int tid = threadIdx.x;
  const int w = tid >> 6, l = tid & 63;
  const int col0 = bx * 128;
  const int row0 = by * 128;
  const int kbeg = bz * kchunk;
  const int kend = kbeg + kchunk;
  const int wm = w >> 1, wn = w & 1;

  f32x4 acc[4][4];
#pragma unroll
  for (int i = 0; i < 4; ++i)
#pragma unroll
    for (int j = 0; j < 4; ++j) acc[i][j] = (f32x4)(0.f);

  const int srow = l >> 3;
  const int sslot = l & 7;

#define STAGE4(dst, src, rbase)                                            \
  {                                                                        \
    _Pragma("unroll") for (int i = 0; i < 4; ++i) {                        \
      int r = (w * 4 + i) * 8 + srow;                                      \
      const char* gp =                                                     \
          (const char*)(src + (size_t)(rbase + r) * K + k0) + sslot * 16;  \
      short* lp = dst + (w * 4 + i) * 512;                                 \
      __builtin_amdgcn_global_load_lds(                                    \
          (const __attribute__((address_space(1))) unsigned int*)gp,       \
          (__attribute__((address_space(3))) unsigned int*)lp, 16, 0, 0);  \
    }                                                                      \
  }

  for (int k0 = kbeg; k0 < kend; k0 += 64) {
    __syncthreads();
    STAGE4(Ash, Ah, row0)
    STAGE4(Asl, Al, row0)
    STAGE4(Bsh, Bh, col0)
    STAGE4(Bsl, Bl, col0)
    __syncthreads();
#pragma unroll
    for (int kc = 0; kc < 2; ++kc) {
      short8 ah[4], al[4], bh[4], bl[4];
#pragma unroll
      for (int mi = 0; mi < 4; ++mi) {
        int row = wm * 64 + mi * 16 + (l & 15);
        int slot = (kc * 4 + (l >> 4)) ^ (row & 7);
        ah[mi] = *(const short8*)&Ash[row * 64 + slot * 8];
        al[mi] = *(const short8*)&Asl[row * 64 + slot * 8];
      }
#pragma unroll
      for (int ni = 0; ni < 4; ++ni) {
        int row = wn * 64 + ni * 16 + (l & 15);
        int slot = (kc * 4 + (l >> 4)) ^ (row & 7);
        bh[ni] = *(const short8*)&Bsh[row * 64 + slot * 8];
        bl[ni] = *(const short8*)&Bsl[row * 64 + slot * 8];
      }
#pragma unroll
      for (int mi = 0; mi < 4; ++mi)
#pragma unroll
        for (int ni = 0; ni < 4; ++ni) {
          acc[mi][ni] = __builtin_amdgcn_mfma_f32_16x16x32_bf16(
              ah[mi], bh[ni], acc[mi][ni], 0, 0, 0);
          acc[mi][ni] = __builtin_amdgcn_mfma_f32_16x16x32_bf16(
              ah[mi], bl[ni], acc[mi][ni], 0, 0, 0);
          acc[mi][ni] = __builtin_amdgcn_mfma_f32_16x16x32_bf16(
              al[mi], bh[ni], acc[mi][ni], 0, 0, 0);
        }
    }
  }
#undef STAGE4

#pragma unroll
  for (int mi = 0; mi < 4; ++mi) {
#pragma unroll
    for (int ni = 0; ni < 4; ++ni) {
      int row = row0 + wm * 64 + mi * 16 + (l >> 4) * 4;
      int col = col0 + wn * 64 + ni * 16 + (l & 15);
      if (out32) {
        float bc = bias ? bias[col] : 0.f;
#pragma unroll
        for (int r = 0; r < 4; ++r)
          if (row + r < M)
            out32[(size_t)(row + r) * N + col] = acc[mi][ni][r] + bc;
      } else {
        float* Pz = P + (size_t)bz * M * N;
#pragma unroll
        for (int r = 0; r < 4; ++r)
          if (row + r < M) Pz[(size_t)(row + r) * N + col] = acc[mi][ni][r];
      }
    }
  }
}

__device__ void epi_body(const float* __restrict__ P, int nsplit, int M, int N,
                         const float* __restrict__ bias,
                         const float* __restrict__ res,
                         float* __restrict__ out32, short* __restrict__ o16h,
                         short* __restrict__ o16l, int act,
                         const float* __restrict__ g,
                         const float* __restrict__ bln,
                         short* __restrict__ z16h, short* __restrict__ z16l,
                         int r, char* smem) {
  float* sb = (float*)smem;
  float myval = 0.f;
  for (int c = threadIdx.x; c < N; c += 256) {
    float acc = 0.f;
    for (int s = 0; s < nsplit; ++s)
      acc += P[(long long)s * M * N + (long long)r * N + c];
    acc += bias[c];
    if (act) acc = gelu_f(acc);
    if (res) acc += res[(long long)r * N + c];
    if (out32) out32[(long long)r * N + c] = acc;
    if (o16h) {
      short h, L;
      split2(acc, h, L);
      o16h[(long long)r * N + swz(c, r)] = h;
      o16l[(long long)r * N + swz(c, r)] = L;
    }
    myval = acc;
  }
  if (z16h) {
    float mean = block_sum_256(myval, sb) * (1.f / 256.f);
    float dv = myval - mean;
    float var = block_sum_256(dv * dv, sb) * (1.f / 256.f);
    float z = dv * rsqrtf(var + 1e-5f) * g[threadIdx.x] + bln[threadIdx.x];
    short h, L;
    split2(z, h, L);
    z16h[r * 256 + swz((int)threadIdx.x, r)] = h;
    z16l[r * 256 + swz((int)threadIdx.x, r)] = L;
  }
}

#define AROWS 17
__device__ void attn_body(const float* __restrict__ qkv,
                          short* __restrict__ Oh, short* __restrict__ Ol,
                          int sx, int bh, char* smem) {
  float(*qs)[256] = (float(*)[256])smem;
  float(*Ks)[68] = (float(*)[68])(smem + 18432);
  float(*ps)[66] = (float(*)[66])(smem + 36928);
  const int tid = threadIdx.x;
  const int s0 = sx * AROWS;
  const int b = bh >> 4, h = bh & 15;
  const long long base = (long long)(b * 65) * 12288 + h * 768;

#pragma unroll
  for (int i = 0; i < AROWS; ++i) {
    int s = s0 + i;
    qs[i][tid] = (s < 65) ? qkv[base + (long long)s * 12288 + tid] : 0.f;
  }

  const int up = tid / 17, tg = tid % 17;
  const int i0 = up * 2, t0 = tg * 4;
  const bool uval = (tid < 153);
  float acc[2][4] = {};
  for (int dc = 0; dc < 256; dc += 64) {
    __syncthreads();
    for (int idx = tid; idx < 65 * 64; idx += 256) {
      int t = idx >> 6, dd = idx & 63;
      Ks[t][dd] = qkv[base + (long long)t * 12288 + 256 + dc + dd];
    }
    __syncthreads();
    if (uval) {
#pragma unroll
      for (int d4 = 0; d4 < 64; d4 += 4) {
        float4 qa = *(const float4*)&qs[i0][dc + d4];
        float4 qb = *(const float4*)&qs[i0 + 1][dc + d4];
#pragma unroll
        for (int c = 0; c < 4; ++c) {
          float4 kv = *(const float4*)&Ks[t0 + c][d4];
          acc[0][c] += qa.x * kv.x + qa.y * kv.y + qa.z * kv.z + qa.w * kv.w;
          acc[1][c] += qb.x * kv.x + qb.y * kv.y + qb.z * kv.z + qb.w * kv.w;
        }
      }
    }
  }
  if (uval) {
#pragma unroll
    for (int ii = 0; ii < 2; ++ii) {
      int i = i0 + ii;
      if (i < AROWS && (s0 + i) < 65) {
#pragma unroll
        for (int c = 0; c < 4; ++c) {
          int t = t0 + c;
          if (t < 65) ps[i][t] = acc[ii][c] * 0.25f;
        }
      }
    }
  }
  __syncthreads();

  if (tid < AROWS && (s0 + tid) < 65) {
    float* row = ps[tid];
    float m = row[0];
    for (int t = 1; t < 65; ++t) m = fmaxf(m, row[t]);
    float sum = 0.f;
    for (int t = 0; t < 65; ++t) {
      float e = expf(row[t] - m);
      row[t] = e;
      sum += e;
    }
    float inv = 1.f / sum;
    for (int t = 0; t < 65; ++t) row[t] *= inv;
  }
  __syncthreads();

  float oacc[AROWS];
#pragma unroll
  for (int i = 0; i < AROWS; ++i) oacc[i] = 0.f;
  const float* vp = qkv + base + 512 + tid;
  for (int t = 0; t < 65; ++t) {
    float vtd = vp[(long long)t * 12288];
#pragma unroll
    for (int i = 0; i < AROWS; ++i) oacc[i] += ps[i][t] * vtd;
  }
#pragma unroll
  for (int i = 0; i < AROWS; ++i) {
    int s = s0 + i;
    if (s < 65) {
      int row = b * 65 + s;
      int col = h * 256 + ((tid & ~63) | ((tid & 63) ^ ((row & 7) << 3)));
      short hh, LL;
      split2(oacc[i], hh, LL);
      Oh[(long long)row * 4096 + col] = hh;
      Ol[(long long)row * 4096 + col] = LL;
    }
  }
}

__device__ void head_body(const float* __restrict__ A, int lda,
                          const float* __restrict__ B,
                          const float* __restrict__ bias, float* __restrict__ C,
                          int N, int K, int KS, int act, int bx, int r,
                          char* smem) {
  float* red = (float*)smem;
  const int COLS = 256 / KS;
  const int tid = threadIdx.x;
  const int lane = tid % COLS;
  const int ks = tid / COLS;
  const int c = bx * COLS + lane;
  float acc = 0.f;
  const int kc = K / KS;
  if (c < N) {
    const float* ap = A + (long long)r * lda + ks * kc;
    const float* bp = B + (long long)(ks * kc) * N + c;
    for (int k = 0; k < kc; ++k) acc += ap[k] * bp[(long long)k * N];
  }
  __syncthreads();
  red[ks * COLS + lane] = acc;
  __syncthreads();
  if (ks == 0 && c < N) {
    float v = bias[c];
    for (int s = 0; s < KS; ++s) v += red[s * COLS + lane];
    if (act) v = gelu_f(v);
    C[(long long)r * N + c] = v;
  }
}

// ---------------- the megakernel ----------------
__global__ __launch_bounds__(256, 2) void mega_kernel(MegaArgs a) {
  __shared__ __align__(16) char smem[65536];
  const int nb = gridDim.x;
  const int bid = blockIdx.x;
  int e = 0;
  const int M = 520;

  for (int t = bid; t < 520; t += nb) embed_body(a, t, smem);
  gsync(a.arrive, a.go, ++e, nb);

  for (int l = 0; l < 24; ++l) {
    const short* Wqh = a.Wqh + (long long)l * 3145728;
    const short* Wql = a.Wql + (long long)l * 3145728;
    const short* Woh = a.Woh + (long long)l * 1048576;
    const short* Wol = a.Wol + (long long)l * 1048576;
    const short* W1h = a.W1h + (long long)l * 262144;
    const short* W1l = a.W1l + (long long)l * 262144;
    const short* W2h = a.W2h + (long long)l * 262144;
    const short* W2l = a.W2l + (long long)l * 262144;

    // QKV gemm: 96x5 tiles, full K
    for (int t = bid; t < 480; t += nb)
      gemm_body(a.zh, a.zl, Wqh, Wql, M, 12288, 256, 256, a.bqkv + l * 12288,
                a.qkvf, nullptr, t % 96, t / 96, 0, smem);
    gsync(a.arrive, a.go, ++e, nb);

    // attention: 4 x 128
    for (int t = bid; t < 512; t += nb)
      attn_body(a.qkvf, a.Oh, a.Ol, t & 3, t >> 2, smem);
    gsync(a.arrive, a.go, ++e, nb);

    // Wo gemm: 2x5x32 split-K (kchunk 128)
    for (int t = bid; t < 320; t += nb)
      gemm_body(a.Oh, a.Ol, Woh, Wol, M, 256, 4096, 128, nullptr, nullptr,
                a.Pb, t % 2, (t / 2) % 5, t / 10, smem);
    gsync(a.arrive, a.go, ++e, nb);

    // y1 = sum + bo + tok ; z = LN2(y1)
    for (int t = bid; t < 520; t += nb)
      epi_body(a.Pb, 32, M, 256, a.bo + l * 256, a.tok, a.y1, nullptr, nullptr,
               0, a.ln2g + l * 256, a.ln2b + l * 256, a.zh, a.zl, t, smem);
    gsync(a.arrive, a.go, ++e, nb);

    // MLP1 gemm: 8x5x4 split-K (kchunk 64)
    for (int t = bid; t < 160; t += nb)
      gemm_body(a.zh, a.zl, W1h, W1l, M, 1024, 256, 64, nullptr, nullptr, a.Pb,
                t % 8, (t / 8) % 5, t / 40, smem);
    gsync(a.arrive, a.go, ++e, nb);

    // h1 = gelu(sum + b1)
    for (int t = bid; t < 520; t += nb)
      epi_body(a.Pb, 4, M, 1024, a.bm1 + l * 1024, nullptr, nullptr, a.h1h,
               a.h1l, 1, nullptr, nullptr, nullptr, nullptr, t, smem);
    gsync(a.arrive, a.go, ++e, nb);

    // MLP2 gemm: 2x5x16 split-K (kchunk 64)
    for (int t = bid; t < 160; t += nb)
      gemm_body(a.h1h, a.h1l, W2h, W2l, M, 256, 1024, 64, nullptr, nullptr,
                a.Pb, t % 2, (t / 2) % 5, t / 10, smem);
    gsync(a.arrive, a.go, ++e, nb);

    // tok = gelu(sum + b2) + y1 ; z = LN1_{l+1}(tok)
    const float* ng = (l < 23) ? a.ln1g + (l + 1) * 256 : nullptr;
    const float* nbb = (l < 23) ? a.ln1b + (l + 1) * 256 : nullptr;
    short* nzh = (l < 23) ? a.zh : nullptr;
    short* nzl = (l < 23) ? a.zl : nullptr;
    for (int t = bid; t < 520; t += nb)
      epi_body(a.Pb, 16, M, 256, a.bm2 + l * 256, a.y1, a.tok, nullptr,
               nullptr, 1, ng, nbb, nzh, nzl, t, smem);
    gsync(a.arrive, a.go, ++e, nb);
  }

  // classification head on cls token (row stride 65*256 picks s==0)
  for (int t = bid; t < 128; t += nb)
    head_body(a.tok, 16640, a.Wh1, a.bh1, a.hh1, 1024, 256, 4, 1, t % 16,
              t / 16, smem);
  gsync(a.arrive, a.go, ++e, nb);
  for (int t = bid; t < 64; t += nb)
    head_body(a.hh1, 1024, a.Wh2, a.bh2, a.hh2, 256, 1024, 8, 1, t % 8, t / 8,
              smem);
  gsync(a.arrive, a.go, ++e, nb);
  for (int t = bid; t < 128; t += nb)
    head_body(a.hh2, 256, a.Wh3, a.bh3, a.out, 1000, 256, 4, 0, t % 16, t / 16,
              smem);
}

extern "C" void kernel_launch(void* const* d_in, const int* in_sizes, int n_in,
                              void* d_out, int out_size, void* d_ws,
                              size_t ws_size, hipStream_t stream) {
  const float* x = (const float*)d_in[0];
  const float* conv_w = (const float*)d_in[1];
  const float* conv_b = (const float*)d_in[2];
  const float* cls = (const float*)d_in[3];
  const float* pos = (const float*)d_in[4];
  const float* Wqkv = (const float*)d_in[5];
  const float* bqkv = (const float*)d_in[6];
  const float* Wo = (const float*)d_in[7];
  const float* bo = (const float*)d_in[8];
  const float* ln1g = (const float*)d_in[9];
  const float* ln1b = (const float*)d_in[10];
  const float* ln2g = (const float*)d_in[11];
  const float* ln2b = (const float*)d_in[12];
  const float* Wm1 = (const float*)d_in[13];
  const float* bm1 = (const float*)d_in[14];
  const float* Wm2 = (const float*)d_in[15];
  const float* bm2 = (const float*)d_in[16];

  // ---- workspace map (float units) ----
  float* ws = (float*)d_ws;
  int* arrive = (int*)ws;                     // [0,8192) ints (512 x 64B)
  int* go = (int*)ws + 8192;                  // [8192,16384) ints
  float* tok = ws + 16384;                    // 640x256
  float* y1 = ws + 180224;                    // 640x256
  float* Pb = ws + 344064;                    // 32x520x256 = 4,259,840
  float* qkvf = ws + 4603904;                 // 520x12288 = 6,389,760
  short* zh = (short*)(ws + 10993664);        // 640x256 bf16
  short* zl = (short*)(ws + 11075584);
  short* Oh = (short*)(ws + 11157504);        // 640x4096 bf16
  short* Ol = (short*)(ws + 12468224);
  short* h1h = (short*)(ws + 13778944);       // 640x1024 bf16
  short* h1l = (short*)(ws + 14106624);
  float* hh1 = ws + 14434304;                 // 8x1024
  float* hh2 = ws + 14442496;                 // 8x256
  short* Wqh = (short*)(ws + 14444544);       // 24x12288x256 bf16
  short* Wql = (short*)(ws + 52193280);
  short* Woh = (short*)(ws + 89942016);       // 24x256x4096
  short* Wol = (short*)(ws + 102524928);
  short* W1h = (short*)(ws + 115107840);      // 24x1024x256
  short* W1l = (short*)(ws + 118253568);
  short* W2h = (short*)(ws + 121399296);      // 24x256x1024
  short* W2l = (short*)(ws + 124545024);

  // weight convert + transpose (every launch; deterministic)
  convert_w<<<dim3(192, 2, 24), 256, 0, stream>>>(
      Wqkv, Wqh, Wql, 256, 12288, 768, 768, 196608LL, 3145728LL, 3145728LL);
  convert_w<<<dim3(4, 32, 24), 256, 0, stream>>>(
      Wo, Woh, Wol, 4096, 256, 256, 1 << 30, 0LL, 1048576LL, 1048576LL);
  convert_w<<<dim3(16, 2, 24), 256, 0, stream>>>(
      Wm1, W1h, W1l, 256, 1024, 1024, 1 << 30, 0LL, 262144LL, 262144LL);
  convert_w<<<dim3(4, 8, 24), 256, 0, stream>>>(
      Wm2, W2h, W2l, 1024, 256, 256, 1 << 30, 0LL, 262144LL, 262144LL);

  // zero barrier flags (captured in graph -> re-zeroed every replay)
  hipMemsetAsync(arrive, 0, 16384 * sizeof(int), stream);

  int dev = 0;
  hipGetDevice(&dev);
  int mpc = 256;
  hipDeviceGetAttribute(&mpc, hipDeviceAttributeMultiprocessorCount, dev);
  int nb = mpc * 2;  // LDS 64KB -> exactly 2 blocks/CU co-resident
  if (nb > 512) nb = 512;

  MegaArgs a;
  a.x = x; a.cw = conv_w; a.cb = conv_b; a.cls = cls; a.pos = pos;
  a.bqkv = bqkv; a.bo = bo; a.ln1g = ln1g; a.ln1b = ln1b;
  a.ln2g = ln2g; a.ln2b = ln2b; a.bm1 = bm1; a.bm2 = bm2;
  a.Wh1 = (const float*)d_in[17]; a.bh1 = (const float*)d_in[18];
  a.Wh2 = (const float*)d_in[19]; a.bh2 = (const float*)d_in[20];
  a.Wh3 = (const float*)d_in[21]; a.bh3 = (const float*)d_in[22];
  a.out = (float*)d_out;
  a.arrive = arrive; a.go = go;
  a.tok = tok; a.y1 = y1; a.Pb = Pb; a.qkvf = qkvf; a.hh1 = hh1; a.hh2 = hh2;
  a.zh = zh; a.zl = zl; a.Oh = Oh; a.Ol = Ol; a.h1h = h1h; a.h1l = h1l;
  a.Wqh = Wqh; a.Wql = Wql; a.Woh = Woh; a.Wol = Wol;
  a.W1h = W1h; a.W1l = W1l; a.W2h = W2h; a.W2l = W2l;

  mega_kernel<<<nb, 256, 0, stream>>>(a);
}

// Round 8
// 3403.992 us; speedup vs baseline: 7.2253x; 7.2253x over previous
//
#include <hip/hip_runtime.h>
#include <hip/hip_bf16.h>

typedef __attribute__((ext_vector_type(8))) short short8;
typedef __attribute__((ext_vector_type(4))) float f32x4;

__device__ __forceinline__ float gelu_f(float x) {
  return 0.5f * x * (1.0f + erff(x * 0.70710678118654752440f));
}
__device__ __forceinline__ short f2bf(float f) {
  unsigned u = __float_as_uint(f);
  u += 0x7fffu + ((u >> 16) & 1u);
  return (short)(u >> 16);
}
__device__ __forceinline__ float bf2f(short s) {
  return __uint_as_float(((unsigned)(unsigned short)s) << 16);
}
// hi/lo bf16 split: v = hi + lo + O(2^-18 v)
__device__ __forceinline__ void split2(float v, short& h, short& l) {
  h = f2bf(v);
  l = f2bf(v - bf2f(h));
}
// swizzle a column index within its 64-elem group by row (involution)
__device__ __forceinline__ int swz(int col, int row) {
  return (col & ~63) | ((col & 63) ^ ((row & 7) << 3));
}

__device__ __forceinline__ float block_sum_256(float v, float* sb) {
#pragma unroll
  for (int o = 1; o < 64; o <<= 1) v += __shfl_xor(v, o, 64);
  if ((threadIdx.x & 63) == 0) sb[threadIdx.x >> 6] = v;
  __syncthreads();
  float r = sb[0] + sb[1] + sb[2] + sb[3];
  __syncthreads();
  return r;
}

// ---------------- prep kernel: embed+LN1 and all weight converts ----------
struct PrepArgs {
  const float *x, *cw, *cb, *cls, *pos, *ln1g, *ln1b;
  float* tok;
  short *zh, *zl;
  const float *Wqkv, *Wo, *Wm1, *Wm2;
  short *Wqh, *Wql, *Woh, *Wol, *W1h, *W1l, *W2h, *W2l;
};

// weight transpose+convert: fp32 [K][N] -> bf16 hi/lo [N][K] swizzled rows.
// 64-lane-contiguous reads along n (coalesced 256B/wave per k).
__device__ void conv_body(const float* __restrict__ in,
                          short* __restrict__ outh, short* __restrict__ outl,
                          int K, int ldn, int group, long long gstride, int bx,
                          int by) {
  const int n = bx * 64 + (threadIdx.x & 63);
  const int seg = threadIdx.x >> 6;  // 0..3
  const int k0 = by * 128 + seg * 32;
  if (k0 >= K) return;
  const float* ip = in + (long long)(n / group) * gstride + (n % group);
  float v[32];
#pragma unroll
  for (int i = 0; i < 32; ++i) v[i] = ip[(long long)(k0 + i) * ldn];
  const long long rowbase = (long long)n * K;
  const int grp = (n & 7) << 3;
#pragma unroll
  for (int j = 0; j < 4; ++j) {
    int k = k0 + j * 8;
    int kk = (k & ~63) | ((k & 63) ^ grp);
    short8 sh, sl;
#pragma unroll
    for (int i = 0; i < 8; ++i) {
      short h, L;
      split2(v[j * 8 + i], h, L);
      sh[i] = h;
      sl[i] = L;
    }
    *(short8*)(outh + rowbase + kk) = sh;
    *(short8*)(outl + rowbase + kk) = sl;
  }
}

__global__ __launch_bounds__(256) void prep_kernel(PrepArgs p) {
  __shared__ float sb[4];
  const int t = blockIdx.x;
  if (t < 520) {
    // patch embed + pos emb + LN1(layer0)
    int r = t;  // b*65+s
    int b = r / 65, s = r % 65;
    int d = threadIdx.x;
    float val;
    if (s == 0) {
      val = p.cls[d];
    } else {
      int pp = s - 1, pi = pp >> 3, pj = pp & 7;
      const float* xb = p.x + b * 3072 + pi * 4 * 32 + pj * 4;
      const float* w = p.cw + d * 48;
      float acc = p.cb[d];
#pragma unroll
      for (int c = 0; c < 3; ++c)
#pragma unroll
        for (int i = 0; i < 4; ++i)
#pragma unroll
          for (int j = 0; j < 4; ++j)
            acc += xb[c * 1024 + i * 32 + j] * w[c * 16 + i * 4 + j];
      val = acc;
    }
    val += p.pos[s * 256 + d];
    p.tok[r * 256 + d] = val;
    float mean = block_sum_256(val, sb) * (1.0f / 256.0f);
    float dv = val - mean;
    float var = block_sum_256(dv * dv, sb) * (1.0f / 256.0f);
    float z = dv * rsqrtf(var + 1e-5f) * p.ln1g[d] + p.ln1b[d];
    short h, L;
    split2(z, h, L);
    p.zh[r * 256 + swz(d, r)] = h;
    p.zl[r * 256 + swz(d, r)] = L;
    return;
  }
  const int u = t - 520;
  const int layer = u / 576;
  const int r = u % 576;
  if (r < 384) {
    // Wqkv: K=256, N=12288, ldn=768, head-grouped (group 768, gstride 196608)
    conv_body(p.Wqkv + (long long)layer * 3145728,
              p.Wqh + (long long)layer * 3145728,
              p.Wql + (long long)layer * 3145728, 256, 768, 768, 196608LL,
              r % 192, r / 192);
  } else if (r < 512) {
    int v = r - 384;  // Wo: K=4096, N=256, ldn=256
    conv_body(p.Wo + (long long)layer * 1048576,
              p.Woh + (long long)layer * 1048576,
              p.Wol + (long long)layer * 1048576, 4096, 256, 1 << 30, 0LL,
              v % 4, v / 4);
  } else if (r < 544) {
    int v = r - 512;  // Wm1: K=256, N=1024, ldn=1024
    conv_body(p.Wm1 + (long long)layer * 262144,
              p.W1h + (long long)layer * 262144,
              p.W1l + (long long)layer * 262144, 256, 1024, 1 << 30, 0LL,
              v % 16, v / 16);
  } else {
    int v = r - 544;  // Wm2: K=1024, N=256, ldn=256
    conv_body(p.Wm2 + (long long)layer * 262144,
              p.W2h + (long long)layer * 262144,
              p.W2l + (long long)layer * 262144, 1024, 256, 1 << 30, 0LL,
              v % 4, v / 4);
  }
}

// -------- MFMA bf16x3 GEMM (fp32-quality), 128x128 tile, m97 structure ----
__global__ __launch_bounds__(256) void gemm_x3(
    const short* __restrict__ Ah, const short* __restrict__ Al,
    const short* __restrict__ Bh, const short* __restrict__ Bl, int M, int N,
    int K, int kchunk, const float* __restrict__ bias,
    float* __restrict__ out32, float* __restrict__ P) {
  __shared__ short Ash[128 * 64];
  __shared__ short Asl[128 * 64];
  __shared__ short Bsh[128 * 64];
  __shared__ short Bsl[128 * 64];
  const int tid = threadIdx.x;
  const int w = tid >> 6, l = tid & 63;
  const int col0 = blockIdx.x * 128;
  const int row0 = blockIdx.y * 128;
  const int kbeg = blockIdx.z * kchunk;
  const int kend = kbeg + kchunk;
  const int wm = w >> 1, wn = w & 1;  // 2x2 waves of 64x64

  f32x4 acc[4][4];
#pragma unroll
  for (int i = 0; i < 4; ++i)
#pragma unroll
    for (int j = 0; j < 4; ++j) acc[i][j] = (f32x4)(0.f);

  const int srow = l >> 3;  // row within 8-row chunk
  const int sslot = l & 7;  // 16B slot

#define STAGE4(dst, src, rbase)                                            \
  {                                                                        \
    _Pragma("unroll") for (int i = 0; i < 4; ++i) {                        \
      int r = (w * 4 + i) * 8 + srow;                                      \
      const char* gp =                                                     \
          (const char*)(src + (size_t)(rbase + r) * K + k0) + sslot * 16;  \
      short* lp = dst + (w * 4 + i) * 512;                                 \
      __builtin_amdgcn_global_load_lds(                                    \
          (const __attribute__((address_space(1))) unsigned int*)gp,       \
          (__attribute__((address_space(3))) unsigned int*)lp, 16, 0, 0);  \
    }                                                                      \
  }

  for (int k0 = kbeg; k0 < kend; k0 += 64) {
    __syncthreads();
    STAGE4(Ash, Ah, row0)
    STAGE4(Asl, Al, row0)
    STAGE4(Bsh, Bh, col0)
    STAGE4(Bsl, Bl, col0)
    __syncthreads();
#pragma unroll
    for (int kc = 0; kc < 2; ++kc) {
      short8 ah[4], al[4], bh[4], bl[4];
#pragma unroll
      for (int mi = 0; mi < 4; ++mi) {
        int row = wm * 64 + mi * 16 + (l & 15);
        int slot = (kc * 4 + (l >> 4)) ^ (row & 7);
        ah[mi] = *(const short8*)&Ash[row * 64 + slot * 8];
        al[mi] = *(const short8*)&Asl[row * 64 + slot * 8];
      }
#pragma unroll
      for (int ni = 0; ni < 4; ++ni) {
        int row = wn * 64 + ni * 16 + (l & 15);
        int slot = (kc * 4 + (l >> 4)) ^ (row & 7);
        bh[ni] = *(const short8*)&Bsh[row * 64 + slot * 8];
        bl[ni] = *(const short8*)&Bsl[row * 64 + slot * 8];
      }
#pragma unroll
      for (int mi = 0; mi < 4; ++mi)
#pragma unroll
        for (int ni = 0; ni < 4; ++ni) {
          acc[mi][ni] = __builtin_amdgcn_mfma_f32_16x16x32_bf16(
              ah[mi], bh[ni], acc[mi][ni], 0, 0, 0);
          acc[mi][ni] = __builtin_amdgcn_mfma_f32_16x16x32_bf16(
              ah[mi], bl[ni], acc[mi][ni], 0, 0, 0);
          acc[mi][ni] = __builtin_amdgcn_mfma_f32_16x16x32_bf16(
              al[mi], bh[ni], acc[mi][ni], 0, 0, 0);
        }
    }
  }
#undef STAGE4

#pragma unroll
  for (int mi = 0; mi < 4; ++mi) {
#pragma unroll
    for (int ni = 0; ni < 4; ++ni) {
      int row = row0 + wm * 64 + mi * 16 + (l >> 4) * 4;
      int col = col0 + wn * 64 + ni * 16 + (l & 15);
      if (out32) {
        float bc = bias ? bias[col] : 0.f;
#pragma unroll
        for (int r = 0; r < 4; ++r)
          if (row + r < M)
            out32[(size_t)(row + r) * N + col] = acc[mi][ni][r] + bc;
      } else {
        float* Pz = P + (size_t)blockIdx.z * M * N;
#pragma unroll
        for (int r = 0; r < 4; ++r)
          if (row + r < M) Pz[(size_t)(row + r) * N + col] = acc[mi][ni][r];
      }
    }
  }
}

// ---------------- split-K reduce + bias + act + residual (+ LN) ----------
__global__ __launch_bounds__(256) void epilogue_kernel(
    const float* __restrict__ P, int nsplit, int M, int N,
    const float* __restrict__ bias, const float* __restrict__ res,
    float* __restrict__ out32, short* __restrict__ o16h,
    short* __restrict__ o16l, int act, const float* __restrict__ g,
    const float* __restrict__ bln, short* __restrict__ z16h,
    short* __restrict__ z16l) {
  __shared__ float sb[4];
  int r = blockIdx.x;
  float myval = 0.f;
  for (int c = threadIdx.x; c < N; c += 256) {
    float acc = 0.f;
    for (int s = 0; s < nsplit; ++s)
      acc += P[(long long)s * M * N + (long long)r * N + c];
    acc += bias[c];
    if (act) acc = gelu_f(acc);
    if (res) acc += res[(long long)r * N + c];
    if (out32) out32[(long long)r * N + c] = acc;
    if (o16h) {
      short h, L;
      split2(acc, h, L);
      o16h[(long long)r * N + swz(c, r)] = h;
      o16l[(long long)r * N + swz(c, r)] = L;
    }
    myval = acc;
  }
  if (z16h) {  // N==256 only
    float mean = block_sum_256(myval, sb) * (1.f / 256.f);
    float dv = myval - mean;
    float var = block_sum_256(dv * dv, sb) * (1.f / 256.f);
    float z = dv * rsqrtf(var + 1e-5f) * g[threadIdx.x] + bln[threadIdx.x];
    short h, L;
    split2(z, h, L);
    z16h[r * 256 + swz((int)threadIdx.x, r)] = h;
    z16l[r * 256 + swz((int)threadIdx.x, r)] = L;
  }
}

// ------- attention (fp32 qkv in, hi/lo bf16 out), 17 q-rows per block -----
#define AROWS 17
__global__ __launch_bounds__(256) void attn_kernel(const float* __restrict__ qkv,
                                                   short* __restrict__ Oh,
                                                   short* __restrict__ Ol) {
  __shared__ float qs[AROWS + 1][256];
  __shared__ float Ks[68][68];
  __shared__ float ps[AROWS][66];
  const int tid = threadIdx.x;
  const int s0 = blockIdx.x * AROWS;
  const int bh = blockIdx.y;
  const int b = bh >> 4, h = bh & 15;
  const long long base = (long long)(b * 65) * 12288 + h * 768;

#pragma unroll
  for (int i = 0; i < AROWS; ++i) {
    int s = s0 + i;
    qs[i][tid] = (s < 65) ? qkv[base + (long long)s * 12288 + tid] : 0.f;
  }

  const int up = tid / 17, tg = tid % 17;
  const int i0 = up * 2, t0 = tg * 4;
  const bool uval = (tid < 153);
  float acc[2][4] = {};
  for (int dc = 0; dc < 256; dc += 64) {
    __syncthreads();
    for (int idx = tid; idx < 65 * 64; idx += 256) {
      int t = idx >> 6, dd = idx & 63;
      Ks[t][dd] = qkv[base + (long long)t * 12288 + 256 + dc + dd];
    }
    __syncthreads();
    if (uval) {
#pragma unroll
      for (int d4 = 0; d4 < 64; d4 += 4) {
        float4 qa = *(const float4*)&qs[i0][dc + d4];
        float4 qb = *(const float4*)&qs[i0 + 1][dc + d4];
#pragma unroll
        for (int c = 0; c < 4; ++c) {
          float4 kv = *(const float4*)&Ks[t0 + c][d4];
          acc[0][c] += qa.x * kv.x + qa.y * kv.y + qa.z * kv.z + qa.w * kv.w;
          acc[1][c] += qb.x * kv.x + qb.y * kv.y + qb.z * kv.z + qb.w * kv.w;
        }
      }
    }
  }
  if (uval) {
#pragma unroll
    for (int ii = 0; ii < 2; ++ii) {
      int i = i0 + ii;
      if (i < AROWS && (s0 + i) < 65) {
#pragma unroll
        for (int c = 0; c < 4; ++c) {
          int t = t0 + c;
          if (t < 65) ps[i][t] = acc[ii][c] * 0.25f;
        }
      }
    }
  }
  __syncthreads();

  if (tid < AROWS && (s0 + tid) < 65) {
    float* row = ps[tid];
    float m = row[0];
    for (int t = 1; t < 65; ++t) m = fmaxf(m, row[t]);
    float sum = 0.f;
    for (int t = 0; t < 65; ++t) {
      float e = expf(row[t] - m);
      row[t] = e;
      sum += e;
    }
    float inv = 1.f / sum;
    for (int t = 0; t < 65; ++t) row[t] *= inv;
  }
  __syncthreads();

  float oacc[AROWS];
#pragma unroll
  for (int i = 0; i < AROWS; ++i) oacc[i] = 0.f;
  const float* vp = qkv + base + 512 + tid;
  for (int t = 0; t < 65; ++t) {
    float vtd = vp[(long long)t * 12288];
#pragma unroll
    for (int i = 0; i < AROWS; ++i) oacc[i] += ps[i][t] * vtd;
  }
#pragma unroll
  for (int i = 0; i < AROWS; ++i) {
    int s = s0 + i;
    if (s < 65) {
      int row = b * 65 + s;
      int col = h * 256 + ((tid & ~63) | ((tid & 63) ^ ((row & 7) << 3)));
      short hh, LL;
      split2(oacc[i], hh, LL);
      Oh[(long long)row * 4096 + col] = hh;
      Ol[(long long)row * 4096 + col] = LL;
    }
  }
}

// ---------------- head GEMMs (fp32, tiny) ----------------
template <int KS>
__global__ __launch_bounds__(256) void head_gemm2(
    const float* __restrict__ A, int lda, const float* __restrict__ B,
    const float* __restrict__ bias, float* __restrict__ C, int N, int K,
    int act) {
  constexpr int COLS = 256 / KS;
  __shared__ float red[KS][COLS];
  const int lane = threadIdx.x % COLS;
  const int ks = threadIdx.x / COLS;
  const int c = blockIdx.x * COLS + lane;
  const int r = blockIdx.y;
  const float* a = A + (long long)r * lda;
  float acc = 0.f;
  const int kc = K / KS;
  if (c < N) {
    const float* ap = a + ks * kc;
    const float* bp = B + (long long)(ks * kc) * N + c;
#pragma unroll 8
    for (int k = 0; k < kc; ++k) acc += ap[k] * bp[(long long)k * N];
  }
  red[ks][lane] = acc;
  __syncthreads();
  if (ks == 0 && c < N) {
    float v = bias[c];
#pragma unroll
    for (int s = 0; s < KS; ++s) v += red[s][lane];
    if (act) v = gelu_f(v);
    C[(long long)r * N + c] = v;
  }
}

extern "C" void kernel_launch(void* const* d_in, const int* in_sizes, int n_in,
                              void* d_out, int out_size, void* d_ws,
                              size_t ws_size, hipStream_t stream) {
  const float* x = (const float*)d_in[0];
  const float* conv_w = (const float*)d_in[1];
  const float* conv_b = (const float*)d_in[2];
  const float* cls = (const float*)d_in[3];
  const float* pos = (const float*)d_in[4];
  const float* Wqkv = (const float*)d_in[5];
  const float* bqkv = (const float*)d_in[6];
  const float* Wo = (const float*)d_in[7];
  const float* bo = (const float*)d_in[8];
  const float* ln1g = (const float*)d_in[9];
  const float* ln1b = (const float*)d_in[10];
  const float* ln2g = (const float*)d_in[11];
  const float* ln2b = (const float*)d_in[12];
  const float* Wm1 = (const float*)d_in[13];
  const float* bm1 = (const float*)d_in[14];
  const float* Wm2 = (const float*)d_in[15];
  const float* bm2 = (const float*)d_in[16];
  const float* Wh1 = (const float*)d_in[17];
  const float* bh1 = (const float*)d_in[18];
  const float* Wh2 = (const float*)d_in[19];
  const float* bh2 = (const float*)d_in[20];
  const float* Wh3 = (const float*)d_in[21];
  const float* bh3 = (const float*)d_in[22];
  float* out = (float*)d_out;

  // ---- workspace map (float units; identical to round-5 proven map) ----
  float* ws = (float*)d_ws;
  float* tok = ws;
  float* y1 = ws + 163840;
  float* Pb = ws + 327680;
  float* qkvf = ws + 2457600;
  short* zh = (short*)(ws + 8847360);
  short* zl = (short*)(ws + 8929280);
  short* Oh = (short*)(ws + 9011200);
  short* Ol = (short*)(ws + 10321920);
  short* h1h = (short*)(ws + 11632640);
  short* h1l = (short*)(ws + 11960320);
  float* hh1 = ws + 12288000;
  float* hh2 = ws + 12296192;
  short* Wqh = (short*)(ws + 12298240);
  short* Wql = (short*)(ws + 50046976);
  short* Woh = (short*)(ws + 87795712);
  short* Wol_ = (short*)(ws + 100378624);
  short* W1h = (short*)(ws + 112961536);
  short* W1l = (short*)(ws + 116107264);
  short* W2h = (short*)(ws + 119252992);
  short* W2l = (short*)(ws + 122398720);

  const int M = 520;

  // one prep dispatch: embed+LN1 (520 blocks) + all weight converts
  PrepArgs p;
  p.x = x; p.cw = conv_w; p.cb = conv_b; p.cls = cls; p.pos = pos;
  p.ln1g = ln1g; p.ln1b = ln1b;
  p.tok = tok; p.zh = zh; p.zl = zl;
  p.Wqkv = Wqkv; p.Wo = Wo; p.Wm1 = Wm1; p.Wm2 = Wm2;
  p.Wqh = Wqh; p.Wql = Wql; p.Woh = Woh; p.Wol = Wol_;
  p.W1h = W1h; p.W1l = W1l; p.W2h = W2h; p.W2l = W2l;
  prep_kernel<<<520 + 24 * 576, 256, 0, stream>>>(p);

  for (int l = 0; l < 24; ++l) {
    const short* Wqhl = Wqh + (long long)l * 3145728;
    const short* Wqll = Wql + (long long)l * 3145728;
    const short* Wohl = Woh + (long long)l * 1048576;
    const short* Woll = Wol_ + (long long)l * 1048576;
    const short* W1hl = W1h + (long long)l * 262144;
    const short* W1ll = W1l + (long long)l * 262144;
    const short* W2hl = W2h + (long long)l * 262144;
    const short* W2ll = W2l + (long long)l * 262144;
    const float* bq = bqkv + l * 12288;
    const float* bol = bo + l * 256;
    const float* b1 = bm1 + l * 1024;
    const float* b2 = bm2 + l * 256;

    // QKV: z @ Wq -> qkvf fp32 (+bias)
    gemm_x3<<<dim3(96, 5, 1), 256, 0, stream>>>(zh, zl, Wqhl, Wqll, M, 12288,
                                                256, 256, bq, qkvf, nullptr);

    attn_kernel<<<dim3(4, 128), 256, 0, stream>>>(qkvf, Oh, Ol);

    // Wo: O(520x4096) @ Wo'(256x4096), split-K 16
    gemm_x3<<<dim3(2, 5, 16), 256, 0, stream>>>(Oh, Ol, Wohl, Woll, M, 256,
                                                4096, 256, nullptr, nullptr,
                                                Pb);
    epilogue_kernel<<<520, 256, 0, stream>>>(
        Pb, 16, M, 256, bol, tok, y1, nullptr, nullptr, 0, ln2g + l * 256,
        ln2b + l * 256, zh, zl);

    // MLP1: z @ Wm1'(1024x256), split-K 4, gelu -> h1 hi/lo
    gemm_x3<<<dim3(8, 5, 4), 256, 0, stream>>>(zh, zl, W1hl, W1ll, M, 1024,
                                               256, 64, nullptr, nullptr, Pb);
    epilogue_kernel<<<520, 256, 0, stream>>>(Pb, 4, M, 1024, b1, nullptr,
                                             nullptr, h1h, h1l, 1, nullptr,
                                             nullptr, nullptr, nullptr);

    // MLP2: h1 @ Wm2'(256x1024), split-K 16, gelu, +y1 -> tok
    gemm_x3<<<dim3(2, 5, 16), 256, 0, stream>>>(h1h, h1l, W2hl, W2ll, M, 256,
                                                1024, 64, nullptr, nullptr,
                                                Pb);
    const float* ng = (l < 23) ? ln1g + (l + 1) * 256 : nullptr;
    const float* nb = (l < 23) ? ln1b + (l + 1) * 256 : nullptr;
    short* nzh = (l < 23) ? zh : nullptr;
    short* nzl = (l < 23) ? zl : nullptr;
    epilogue_kernel<<<520, 256, 0, stream>>>(Pb, 16, M, 256, b2, y1, tok,
                                             nullptr, nullptr, 1, ng, nb, nzh,
                                             nzl);
  }

  head_gemm2<4><<<dim3(16, 8), 256, 0, stream>>>(tok, 16640, Wh1, bh1, hh1,
                                                 1024, 256, 1);
  head_gemm2<8><<<dim3(8, 8), 256, 0, stream>>>(hh1, 1024, Wh2, bh2, hh2, 256,
                                                1024, 1);
  head_gemm2<4><<<dim3(16, 8), 256, 0, stream>>>(hh2, 256, Wh3, bh3, out, 1000,
                                                 256, 0);
}

// Round 9
// 3163.066 us; speedup vs baseline: 7.7756x; 1.0762x over previous
//
#include <hip/hip_runtime.h>
#include <hip/hip_bf16.h>

typedef __attribute__((ext_vector_type(8))) short short8;
typedef __attribute__((ext_vector_type(4))) float f32x4;

__device__ __forceinline__ float gelu_f(float x) {
  return 0.5f * x * (1.0f + erff(x * 0.70710678118654752440f));
}
__device__ __forceinline__ short f2bf(float f) {
  unsigned u = __float_as_uint(f);
  u += 0x7fffu + ((u >> 16) & 1u);
  return (short)(u >> 16);
}
__device__ __forceinline__ float bf2f(short s) {
  return __uint_as_float(((unsigned)(unsigned short)s) << 16);
}
// hi/lo bf16 split: v = hi + lo + O(2^-18 v)
__device__ __forceinline__ void split2(float v, short& h, short& l) {
  h = f2bf(v);
  l = f2bf(v - bf2f(h));
}
// swizzle a column index within its 64-elem group by row (involution)
__device__ __forceinline__ int swz(int col, int row) {
  return (col & ~63) | ((col & 63) ^ ((row & 7) << 3));
}

__device__ __forceinline__ float block_sum_256(float v, float* sb) {
#pragma unroll
  for (int o = 1; o < 64; o <<= 1) v += __shfl_xor(v, o, 64);
  if ((threadIdx.x & 63) == 0) sb[threadIdx.x >> 6] = v;
  __syncthreads();
  float r = sb[0] + sb[1] + sb[2] + sb[3];
  __syncthreads();
  return r;
}

// ---------------- prep kernel: embed+LN1 and all weight converts ----------
struct PrepArgs {
  const float *x, *cw, *cb, *cls, *pos, *ln1g, *ln1b;
  float* tok;
  short *zh, *zl;
  const float *Wqkv, *Wo, *Wm1, *Wm2;
  short *Wqh, *Wql, *Woh, *Wol, *W1h, *W1l, *W2h, *W2l;
};

// weight transpose+convert: fp32 [K][N] -> bf16 hi/lo [N][K] swizzled rows.
// LDS-transpose version: reads are float4/lane along N (4x 1KB contiguous
// segments per instr), writes one output row per thread (identical layout
// to previous rounds: out[n*K + swz(k,n)]).
// Block covers n-range 256, k-range 32. tile[32][257] padded (conflict-free).
__device__ void conv_body(const float* __restrict__ in,
                          short* __restrict__ outh, short* __restrict__ outl,
                          int K, int ldn, int group, long long gstride, int bx,
                          int by, float* tile /* [32][257] */) {
  const int n0 = bx * 256;
  const int k0 = by * 32;
  const int tid = threadIdx.x;
  // read phase: thread -> k = (tid>>6) + 4*i, n4 = (tid&63)*4
  {
    const int kb = tid >> 6;        // 0..3
    const int n4 = (tid & 63) * 4;  // 0..252
    const int n = n0 + n4;
    const long long nbase = (long long)(n / group) * gstride + (n % group);
#pragma unroll
    for (int i = 0; i < 8; ++i) {
      int k = kb + i * 4;  // 0..31, each exactly once per (kb)
      float4 v4 = *(const float4*)(in + nbase + (long long)(k0 + k) * ldn);
      float* tr = tile + k * 257 + n4;
      tr[0] = v4.x;
      tr[1] = v4.y;
      tr[2] = v4.z;
      tr[3] = v4.w;
    }
  }
  __syncthreads();
  // write phase: thread owns output row n = n0 + tid
  {
    const int r = tid;
    const int n = n0 + r;
    float v[32];
#pragma unroll
    for (int i = 0; i < 32; ++i) v[i] = tile[i * 257 + r];
    const long long rowbase = (long long)n * K;
    const int grp = (n & 7) << 3;
#pragma unroll
    for (int j = 0; j < 4; ++j) {
      int k = k0 + j * 8;
      int kk = (k & ~63) | ((k & 63) ^ grp);
      short8 sh, sl;
#pragma unroll
      for (int i = 0; i < 8; ++i) {
        short h, L;
        split2(v[j * 8 + i], h, L);
        sh[i] = h;
        sl[i] = L;
      }
      *(short8*)(outh + rowbase + kk) = sh;
      *(short8*)(outl + rowbase + kk) = sl;
    }
  }
  __syncthreads();
}

__global__ __launch_bounds__(256) void prep_kernel(PrepArgs p) {
  __shared__ __align__(16) float smem[32 * 257];  // 32.9 KB
  const int t = blockIdx.x;
  if (t < 520) {
    float* sb = smem;
    // patch embed + pos emb + LN1(layer0)
    int r = t;  // b*65+s
    int b = r / 65, s = r % 65;
    int d = threadIdx.x;
    float val;
    if (s == 0) {
      val = p.cls[d];
    } else {
      int pp = s - 1, pi = pp >> 3, pj = pp & 7;
      const float* xb = p.x + b * 3072 + pi * 4 * 32 + pj * 4;
      const float* w = p.cw + d * 48;
      float acc = p.cb[d];
#pragma unroll
      for (int c = 0; c < 3; ++c)
#pragma unroll
        for (int i = 0; i < 4; ++i)
#pragma unroll
          for (int j = 0; j < 4; ++j)
            acc += xb[c * 1024 + i * 32 + j] * w[c * 16 + i * 4 + j];
      val = acc;
    }
    val += p.pos[s * 256 + d];
    p.tok[r * 256 + d] = val;
    float mean = block_sum_256(val, sb) * (1.0f / 256.0f);
    float dv = val - mean;
    float var = block_sum_256(dv * dv, sb) * (1.0f / 256.0f);
    float z = dv * rsqrtf(var + 1e-5f) * p.ln1g[d] + p.ln1b[d];
    short h, L;
    split2(z, h, L);
    p.zh[r * 256 + swz(d, r)] = h;
    p.zl[r * 256 + swz(d, r)] = L;
    return;
  }
  const int u = t - 520;
  const int layer = u / 576;
  const int r = u % 576;
  if (r < 384) {
    // Wqkv: K=256 (8 k-blocks), N=12288 (48 n-blocks), ldn=768, head-grouped
    conv_body(p.Wqkv + (long long)layer * 3145728,
              p.Wqh + (long long)layer * 3145728,
              p.Wql + (long long)layer * 3145728, 256, 768, 768, 196608LL,
              r % 48, r / 48, smem);
  } else if (r < 512) {
    int v = r - 384;  // Wo: K=4096 (128 k-blocks), N=256 (1 n-block)
    conv_body(p.Wo + (long long)layer * 1048576,
              p.Woh + (long long)layer * 1048576,
              p.Wol + (long long)layer * 1048576, 4096, 256, 1 << 30, 0LL, 0,
              v, smem);
  } else if (r < 544) {
    int v = r - 512;  // Wm1: K=256 (8 k-blocks), N=1024 (4 n-blocks)
    conv_body(p.Wm1 + (long long)layer * 262144,
              p.W1h + (long long)layer * 262144,
              p.W1l + (long long)layer * 262144, 256, 1024, 1 << 30, 0LL,
              v % 4, v / 4, smem);
  } else {
    int v = r - 544;  // Wm2: K=1024 (32 k-blocks), N=256 (1 n-block)
    conv_body(p.Wm2 + (long long)layer * 262144,
              p.W2h + (long long)layer * 262144,
              p.W2l + (long long)layer * 262144, 1024, 256, 1 << 30, 0LL, 0,
              v, smem);
  }
}

// -------- MFMA bf16x3 GEMM (fp32-quality), 128x128 tile, m97 structure ----
__global__ __launch_bounds__(256) void gemm_x3(
    const short* __restrict__ Ah, const short* __restrict__ Al,
    const short* __restrict__ Bh, const short* __restrict__ Bl, int M, int N,
    int K, int kchunk, const float* __restrict__ bias,
    float* __restrict__ out32, float* __restrict__ P) {
  __shared__ short Ash[128 * 64];
  __shared__ short Asl[128 * 64];
  __shared__ short Bsh[128 * 64];
  __shared__ short Bsl[128 * 64];
  const int tid = threadIdx.x;
  const int w = tid >> 6, l = tid & 63;
  const int col0 = blockIdx.x * 128;
  const int row0 = blockIdx.y * 128;
  const int kbeg = blockIdx.z * kchunk;
  const int kend = kbeg + kchunk;
  const int wm = w >> 1, wn = w & 1;  // 2x2 waves of 64x64

  f32x4 acc[4][4];
#pragma unroll
  for (int i = 0; i < 4; ++i)
#pragma unroll
    for (int j = 0; j < 4; ++j) acc[i][j] = (f32x4)(0.f);

  const int srow = l >> 3;  // row within 8-row chunk
  const int sslot = l & 7;  // 16B slot

#define STAGE4(dst, src, rbase)                                            \
  {                                                                        \
    _Pragma("unroll") for (int i = 0; i < 4; ++i) {                        \
      int r = (w * 4 + i) * 8 + srow;                                      \
      const char* gp =                                                     \
          (const char*)(src + (size_t)(rbase + r) * K + k0) + sslot * 16;  \
      short* lp = dst + (w * 4 + i) * 512;                                 \
      __builtin_amdgcn_global_load_lds(                                    \
          (const __attribute__((address_space(1))) unsigned int*)gp,       \
          (__attribute__((address_space(3))) unsigned int*)lp, 16, 0, 0);  \
    }                                                                      \
  }

  for (int k0 = kbeg; k0 < kend; k0 += 64) {
    __syncthreads();
    STAGE4(Ash, Ah, row0)
    STAGE4(Asl, Al, row0)
    STAGE4(Bsh, Bh, col0)
    STAGE4(Bsl, Bl, col0)
    __syncthreads();
#pragma unroll
    for (int kc = 0; kc < 2; ++kc) {
      short8 ah[4], al[4], bh[4], bl[4];
#pragma unroll
      for (int mi = 0; mi < 4; ++mi) {
        int row = wm * 64 + mi * 16 + (l & 15);
        int slot = (kc * 4 + (l >> 4)) ^ (row & 7);
        ah[mi] = *(const short8*)&Ash[row * 64 + slot * 8];
        al[mi] = *(const short8*)&Asl[row * 64 + slot * 8];
      }
#pragma unroll
      for (int ni = 0; ni < 4; ++ni) {
        int row = wn * 64 + ni * 16 + (l & 15);
        int slot = (kc * 4 + (l >> 4)) ^ (row & 7);
        bh[ni] = *(const short8*)&Bsh[row * 64 + slot * 8];
        bl[ni] = *(const short8*)&Bsl[row * 64 + slot * 8];
      }
#pragma unroll
      for (int mi = 0; mi < 4; ++mi)
#pragma unroll
        for (int ni = 0; ni < 4; ++ni) {
          acc[mi][ni] = __builtin_amdgcn_mfma_f32_16x16x32_bf16(
              ah[mi], bh[ni], acc[mi][ni], 0, 0, 0);
          acc[mi][ni] = __builtin_amdgcn_mfma_f32_16x16x32_bf16(
              ah[mi], bl[ni], acc[mi][ni], 0, 0, 0);
          acc[mi][ni] = __builtin_amdgcn_mfma_f32_16x16x32_bf16(
              al[mi], bh[ni], acc[mi][ni], 0, 0, 0);
        }
    }
  }
#undef STAGE4

#pragma unroll
  for (int mi = 0; mi < 4; ++mi) {
#pragma unroll
    for (int ni = 0; ni < 4; ++ni) {
      int row = row0 + wm * 64 + mi * 16 + (l >> 4) * 4;
      int col = col0 + wn * 64 + ni * 16 + (l & 15);
      if (out32) {
        float bc = bias ? bias[col] : 0.f;
#pragma unroll
        for (int r = 0; r < 4; ++r)
          if (row + r < M)
            out32[(size_t)(row + r) * N + col] = acc[mi][ni][r] + bc;
      } else {
        float* Pz = P + (size_t)blockIdx.z * M * N;
#pragma unroll
        for (int r = 0; r < 4; ++r)
          if (row + r < M) Pz[(size_t)(row + r) * N + col] = acc[mi][ni][r];
      }
    }
  }
}

// ------ split-K reduce + bias + act + residual (+ LN); NSPLIT unrolled ----
template <int NSPLIT>
__global__ __launch_bounds__(256) void epilogue_kernel(
    const float* __restrict__ P, int M, int N, const float* __restrict__ bias,
    const float* __restrict__ res, float* __restrict__ out32,
    short* __restrict__ o16h, short* __restrict__ o16l, int act,
    const float* __restrict__ g, const float* __restrict__ bln,
    short* __restrict__ z16h, short* __restrict__ z16l) {
  __shared__ float sb[4];
  int r = blockIdx.x;
  float myval = 0.f;
  for (int c = threadIdx.x; c < N; c += 256) {
    const float* pp = P + (long long)r * N + c;
    float acc = 0.f;
#pragma unroll
    for (int s = 0; s < NSPLIT; ++s) acc += pp[(long long)s * M * N];
    acc += bias[c];
    if (act) acc = gelu_f(acc);
    if (res) acc += res[(long long)r * N + c];
    if (out32) out32[(long long)r * N + c] = acc;
    if (o16h) {
      short h, L;
      split2(acc, h, L);
      o16h[(long long)r * N + swz(c, r)] = h;
      o16l[(long long)r * N + swz(c, r)] = L;
    }
    myval = acc;
  }
  if (z16h) {  // N==256 only
    float mean = block_sum_256(myval, sb) * (1.f / 256.f);
    float dv = myval - mean;
    float var = block_sum_256(dv * dv, sb) * (1.f / 256.f);
    float z = dv * rsqrtf(var + 1e-5f) * g[threadIdx.x] + bln[threadIdx.x];
    short h, L;
    split2(z, h, L);
    z16h[r * 256 + swz((int)threadIdx.x, r)] = h;
    z16l[r * 256 + swz((int)threadIdx.x, r)] = L;
  }
}

// ------- attention (fp32 qkv in, hi/lo bf16 out), 17 q-rows per block -----
#define AROWS 17
__global__ __launch_bounds__(256) void attn_kernel(const float* __restrict__ qkv,
                                                   short* __restrict__ Oh,
                                                   short* __restrict__ Ol) {
  __shared__ float qs[AROWS + 1][256];
  __shared__ float Ks[68][68];
  __shared__ float ps[AROWS][66];
  const int tid = threadIdx.x;
  const int s0 = blockIdx.x * AROWS;
  const int bh = blockIdx.y;
  const int b = bh >> 4, h = bh & 15;
  const long long base = (long long)(b * 65) * 12288 + h * 768;

#pragma unroll
  for (int i = 0; i < AROWS; ++i) {
    int s = s0 + i;
    qs[i][tid] = (s < 65) ? qkv[base + (long long)s * 12288 + tid] : 0.f;
  }

  const int up = tid / 17, tg = tid % 17;
  const int i0 = up * 2, t0 = tg * 4;
  const bool uval = (tid < 153);
  float acc[2][4] = {};
  for (int dc = 0; dc < 256; dc += 64) {
    __syncthreads();
    for (int idx = tid; idx < 65 * 64; idx += 256) {
      int t = idx >> 6, dd = idx & 63;
      Ks[t][dd] = qkv[base + (long long)t * 12288 + 256 + dc + dd];
    }
    __syncthreads();
    if (uval) {
#pragma unroll
      for (int d4 = 0; d4 < 64; d4 += 4) {
        float4 qa = *(const float4*)&qs[i0][dc + d4];
        float4 qb = *(const float4*)&qs[i0 + 1][dc + d4];
#pragma unroll
        for (int c = 0; c < 4; ++c) {
          float4 kv = *(const float4*)&Ks[t0 + c][d4];
          acc[0][c] += qa.x * kv.x + qa.y * kv.y + qa.z * kv.z + qa.w * kv.w;
          acc[1][c] += qb.x * kv.x + qb.y * kv.y + qb.z * kv.z + qb.w * kv.w;
        }
      }
    }
  }
  if (uval) {
#pragma unroll
    for (int ii = 0; ii < 2; ++ii) {
      int i = i0 + ii;
      if (i < AROWS && (s0 + i) < 65) {
#pragma unroll
        for (int c = 0; c < 4; ++c) {
          int t = t0 + c;
          if (t < 65) ps[i][t] = acc[ii][c] * 0.25f;
        }
      }
    }
  }
  __syncthreads();

  if (tid < AROWS && (s0 + tid) < 65) {
    float* row = ps[tid];
    float m = row[0];
    for (int t = 1; t < 65; ++t) m = fmaxf(m, row[t]);
    float sum = 0.f;
    for (int t = 0; t < 65; ++t) {
      float e = expf(row[t] - m);
      row[t] = e;
      sum += e;
    }
    float inv = 1.f / sum;
    for (int t = 0; t < 65; ++t) row[t] *= inv;
  }
  __syncthreads();

  float oacc[AROWS];
#pragma unroll
  for (int i = 0; i < AROWS; ++i) oacc[i] = 0.f;
  const float* vp = qkv + base + 512 + tid;
  for (int t = 0; t < 65; ++t) {
    float vtd = vp[(long long)t * 12288];
#pragma unroll
    for (int i = 0; i < AROWS; ++i) oacc[i] += ps[i][t] * vtd;
  }
#pragma unroll
  for (int i = 0; i < AROWS; ++i) {
    int s = s0 + i;
    if (s < 65) {
      int row = b * 65 + s;
      int col = h * 256 + ((tid & ~63) | ((tid & 63) ^ ((row & 7) << 3)));
      short hh, LL;
      split2(oacc[i], hh, LL);
      Oh[(long long)row * 4096 + col] = hh;
      Ol[(long long)row * 4096 + col] = LL;
    }
  }
}

// ---------------- head GEMMs (fp32, tiny) ----------------
template <int KS>
__global__ __launch_bounds__(256) void head_gemm2(
    const float* __restrict__ A, int lda, const float* __restrict__ B,
    const float* __restrict__ bias, float* __restrict__ C, int N, int K,
    int act) {
  constexpr int COLS = 256 / KS;
  __shared__ float red[KS][COLS];
  const int lane = threadIdx.x % COLS;
  const int ks = threadIdx.x / COLS;
  const int c = blockIdx.x * COLS + lane;
  const int r = blockIdx.y;
  const float* a = A + (long long)r * lda;
  float acc = 0.f;
  const int kc = K / KS;
  if (c < N) {
    const float* ap = a + ks * kc;
    const float* bp = B + (long long)(ks * kc) * N + c;
#pragma unroll 8
    for (int k = 0; k < kc; ++k) acc += ap[k] * bp[(long long)k * N];
  }
  red[ks][lane] = acc;
  __syncthreads();
  if (ks == 0 && c < N) {
    float v = bias[c];
#pragma unroll
    for (int s = 0; s < KS; ++s) v += red[s][lane];
    if (act) v = gelu_f(v);
    C[(long long)r * N + c] = v;
  }
}

extern "C" void kernel_launch(void* const* d_in, const int* in_sizes, int n_in,
                              void* d_out, int out_size, void* d_ws,
                              size_t ws_size, hipStream_t stream) {
  const float* x = (const float*)d_in[0];
  const float* conv_w = (const float*)d_in[1];
  const float* conv_b = (const float*)d_in[2];
  const float* cls = (const float*)d_in[3];
  const float* pos = (const float*)d_in[4];
  const float* Wqkv = (const float*)d_in[5];
  const float* bqkv = (const float*)d_in[6];
  const float* Wo = (const float*)d_in[7];
  const float* bo = (const float*)d_in[8];
  const float* ln1g = (const float*)d_in[9];
  const float* ln1b = (const float*)d_in[10];
  const float* ln2g = (const float*)d_in[11];
  const float* ln2b = (const float*)d_in[12];
  const float* Wm1 = (const float*)d_in[13];
  const float* bm1 = (const float*)d_in[14];
  const float* Wm2 = (const float*)d_in[15];
  const float* bm2 = (const float*)d_in[16];
  const float* Wh1 = (const float*)d_in[17];
  const float* bh1 = (const float*)d_in[18];
  const float* Wh2 = (const float*)d_in[19];
  const float* bh2 = (const float*)d_in[20];
  const float* Wh3 = (const float*)d_in[21];
  const float* bh3 = (const float*)d_in[22];
  float* out = (float*)d_out;

  // ---- workspace map (float units; identical to round-5 proven map) ----
  float* ws = (float*)d_ws;
  float* tok = ws;
  float* y1 = ws + 163840;
  float* Pb = ws + 327680;
  float* qkvf = ws + 2457600;
  short* zh = (short*)(ws + 8847360);
  short* zl = (short*)(ws + 8929280);
  short* Oh = (short*)(ws + 9011200);
  short* Ol = (short*)(ws + 10321920);
  short* h1h = (short*)(ws + 11632640);
  short* h1l = (short*)(ws + 11960320);
  float* hh1 = ws + 12288000;
  float* hh2 = ws + 12296192;
  short* Wqh = (short*)(ws + 12298240);
  short* Wql = (short*)(ws + 50046976);
  short* Woh = (short*)(ws + 87795712);
  short* Wol_ = (short*)(ws + 100378624);
  short* W1h = (short*)(ws + 112961536);
  short* W1l = (short*)(ws + 116107264);
  short* W2h = (short*)(ws + 119252992);
  short* W2l = (short*)(ws + 122398720);

  const int M = 520;

  // one prep dispatch: embed+LN1 (520 blocks) + all weight converts
  PrepArgs p;
  p.x = x; p.cw = conv_w; p.cb = conv_b; p.cls = cls; p.pos = pos;
  p.ln1g = ln1g; p.ln1b = ln1b;
  p.tok = tok; p.zh = zh; p.zl = zl;
  p.Wqkv = Wqkv; p.Wo = Wo; p.Wm1 = Wm1; p.Wm2 = Wm2;
  p.Wqh = Wqh; p.Wql = Wql; p.Woh = Woh; p.Wol = Wol_;
  p.W1h = W1h; p.W1l = W1l; p.W2h = W2h; p.W2l = W2l;
  prep_kernel<<<520 + 24 * 576, 256, 0, stream>>>(p);

  for (int l = 0; l < 24; ++l) {
    const short* Wqhl = Wqh + (long long)l * 3145728;
    const short* Wqll = Wql + (long long)l * 3145728;
    const short* Wohl = Woh + (long long)l * 1048576;
    const short* Woll = Wol_ + (long long)l * 1048576;
    const short* W1hl = W1h + (long long)l * 262144;
    const short* W1ll = W1l + (long long)l * 262144;
    const short* W2hl = W2h + (long long)l * 262144;
    const short* W2ll = W2l + (long long)l * 262144;
    const float* bq = bqkv + l * 12288;
    const float* bol = bo + l * 256;
    const float* b1 = bm1 + l * 1024;
    const float* b2 = bm2 + l * 256;

    // QKV: z @ Wq -> qkvf fp32 (+bias)
    gemm_x3<<<dim3(96, 5, 1), 256, 0, stream>>>(zh, zl, Wqhl, Wqll, M, 12288,
                                                256, 256, bq, qkvf, nullptr);

    attn_kernel<<<dim3(4, 128), 256, 0, stream>>>(qkvf, Oh, Ol);

    // Wo: O(520x4096) @ Wo'(256x4096), split-K 16
    gemm_x3<<<dim3(2, 5, 16), 256, 0, stream>>>(Oh, Ol, Wohl, Woll, M, 256,
                                                4096, 256, nullptr, nullptr,
                                                Pb);
    epilogue_kernel<16><<<520, 256, 0, stream>>>(
        Pb, M, 256, bol, tok, y1, nullptr, nullptr, 0, ln2g + l * 256,
        ln2b + l * 256, zh, zl);

    // MLP1: z @ Wm1'(1024x256), split-K 4, gelu -> h1 hi/lo
    gemm_x3<<<dim3(8, 5, 4), 256, 0, stream>>>(zh, zl, W1hl, W1ll, M, 1024,
                                               256, 64, nullptr, nullptr, Pb);
    epilogue_kernel<4><<<520, 256, 0, stream>>>(Pb, M, 1024, b1, nullptr,
                                                nullptr, h1h, h1l, 1, nullptr,
                                                nullptr, nullptr, nullptr);

    // MLP2: h1 @ Wm2'(256x1024), split-K 16, gelu, +y1 -> tok
    gemm_x3<<<dim3(2, 5, 16), 256, 0, stream>>>(h1h, h1l, W2hl, W2ll, M, 256,
                                                1024, 64, nullptr, nullptr,
                                                Pb);
    const float* ng = (l < 23) ? ln1g + (l + 1) * 256 : nullptr;
    const float* nb = (l < 23) ? ln1b + (l + 1) * 256 : nullptr;
    short* nzh = (l < 23) ? zh : nullptr;
    short* nzl = (l < 23) ? zl : nullptr;
    epilogue_kernel<16><<<520, 256, 0, stream>>>(Pb, M, 256, b2, y1, tok,
                                                 nullptr, nullptr, 1, ng, nb,
                                                 nzh, nzl);
  }

  head_gemm2<4><<<dim3(16, 8), 256, 0, stream>>>(tok, 16640, Wh1, bh1, hh1,
                                                 1024, 256, 1);
  head_gemm2<8><<<dim3(8, 8), 256, 0, stream>>>(hh1, 1024, Wh2, bh2, hh2, 256,
                                                1024, 1);
  head_gemm2<4><<<dim3(16, 8), 256, 0, stream>>>(hh2, 256, Wh3, bh3, out, 1000,
                                                 256, 0);
}

// Round 10
// 3091.442 us; speedup vs baseline: 7.9557x; 1.0232x over previous
//
#include <hip/hip_runtime.h>
#include <hip/hip_bf16.h>

typedef __attribute__((ext_vector_type(8))) short short8;
typedef __attribute__((ext_vector_type(4))) float f32x4;

__device__ __forceinline__ float gelu_f(float x) {
  return 0.5f * x * (1.0f + erff(x * 0.70710678118654752440f));
}
__device__ __forceinline__ short f2bf(float f) {
  unsigned u = __float_as_uint(f);
  u += 0x7fffu + ((u >> 16) & 1u);
  return (short)(u >> 16);
}
__device__ __forceinline__ float bf2f(short s) {
  return __uint_as_float(((unsigned)(unsigned short)s) << 16);
}
// hi/lo bf16 split: v = hi + lo + O(2^-18 v)
__device__ __forceinline__ void split2(float v, short& h, short& l) {
  h = f2bf(v);
  l = f2bf(v - bf2f(h));
}
// swizzle a column index within its 64-elem group by row (involution)
__device__ __forceinline__ int swz(int col, int row) {
  return (col & ~63) | ((col & 63) ^ ((row & 7) << 3));
}

__device__ __forceinline__ float block_sum_256(float v, float* sb) {
#pragma unroll
  for (int o = 1; o < 64; o <<= 1) v += __shfl_xor(v, o, 64);
  if ((threadIdx.x & 63) == 0) sb[threadIdx.x >> 6] = v;
  __syncthreads();
  float r = sb[0] + sb[1] + sb[2] + sb[3];
  __syncthreads();
  return r;
}

// ---------------- prep kernel: embed+LN1 and all weight converts ----------
struct PrepArgs {
  const float *x, *cw, *cb, *cls, *pos, *ln1g, *ln1b;
  float* tok;
  short *zh, *zl;
  const float *Wqkv, *Wo, *Wm1, *Wm2;
  short *Wqh, *Wql, *Woh, *Wol, *W1h, *W1l, *W2h, *W2l;
};

// weight transpose+convert v3: fp32 [K][N] -> bf16 hi/lo [N][K] swizzled.
// Block = 128 n x 64 k (FULL swizzle group -> full-cacheline writes, no RFO).
// LDS: 4 element planes [64][33] (scalar stores, bank-conflict-free).
// Output bytes identical to previous rounds: out[n*K + swz(k,n)].
__device__ void conv_body(const float* __restrict__ in,
                          short* __restrict__ outh, short* __restrict__ outl,
                          int K, int ldn, int group, long long gstride, int bx,
                          int by, float* tile /* 4*64*33 floats */) {
  const int n0 = bx * 128;
  const int k0 = by * 64;
  const int tid = threadIdx.x;
  // read phase: lane -> n-quad j=tid&31, k-rows kb*8..kb*8+7 (kb=tid>>5)
  {
    const int j = tid & 31;
    const int kb = tid >> 5;  // 0..7
    const int n = n0 + 4 * j;
    const long long nbase = (long long)(n / group) * gstride + (n % group);
#pragma unroll
    for (int i = 0; i < 8; ++i) {
      const int k = kb * 8 + i;
      float4 v4 = *(const float4*)(in + nbase + (long long)(k0 + k) * ldn);
      tile[0 * 2112 + k * 33 + j] = v4.x;
      tile[1 * 2112 + k * 33 + j] = v4.y;
      tile[2 * 2112 + k * 33 + j] = v4.z;
      tile[3 * 2112 + k * 33 + j] = v4.w;
    }
  }
  __syncthreads();
  // write phase: thread (r=tid>>1, hf=tid&1) writes 64B h + 64B l of row n0+r
  {
    const int r = tid >> 1;
    const int hf = tid & 1;
    const int n = n0 + r;
    const int e = r & 3, jj = r >> 2;
    const int g8 = n & 7;
    const float* te = tile + e * 2112 + jj;
    const long long obase = (long long)n * K + k0;
#pragma unroll
    for (int j2 = 0; j2 < 4; ++j2) {
      const int s = hf * 4 + j2;  // dest octet slot within 64-elem group
      const int m = s ^ g8;       // source octet
      short8 sh, sl;
#pragma unroll
      for (int e8 = 0; e8 < 8; ++e8) {
        float v = te[(m * 8 + e8) * 33];
        short h, L;
        split2(v, h, L);
        sh[e8] = h;
        sl[e8] = L;
      }
      *(short8*)(outh + obase + s * 8) = sh;
      *(short8*)(outl + obase + s * 8) = sl;
    }
  }
  __syncthreads();
}

__global__ __launch_bounds__(256) void prep_kernel(PrepArgs p) {
  __shared__ __align__(16) float smem[4 * 64 * 33];  // 33.8 KB
  const int t = blockIdx.x;
  if (t < 520) {
    float* sb = smem;
    // patch embed + pos emb + LN1(layer0)
    int r = t;  // b*65+s
    int b = r / 65, s = r % 65;
    int d = threadIdx.x;
    float val;
    if (s == 0) {
      val = p.cls[d];
    } else {
      int pp = s - 1, pi = pp >> 3, pj = pp & 7;
      const float* xb = p.x + b * 3072 + pi * 4 * 32 + pj * 4;
      const float* w = p.cw + d * 48;
      float acc = p.cb[d];
#pragma unroll
      for (int c = 0; c < 3; ++c)
#pragma unroll
        for (int i = 0; i < 4; ++i)
#pragma unroll
          for (int j = 0; j < 4; ++j)
            acc += xb[c * 1024 + i * 32 + j] * w[c * 16 + i * 4 + j];
      val = acc;
    }
    val += p.pos[s * 256 + d];
    p.tok[r * 256 + d] = val;
    float mean = block_sum_256(val, sb) * (1.0f / 256.0f);
    float dv = val - mean;
    float var = block_sum_256(dv * dv, sb) * (1.0f / 256.0f);
    float z = dv * rsqrtf(var + 1e-5f) * p.ln1g[d] + p.ln1b[d];
    short h, L;
    split2(z, h, L);
    p.zh[r * 256 + swz(d, r)] = h;
    p.zl[r * 256 + swz(d, r)] = L;
    return;
  }
  const int u = t - 520;
  const int layer = u / 576;
  const int r = u % 576;
  if (r < 384) {
    // Wqkv: K=256 (4 k-blk), N=12288 (96 n-blk), ldn=768, head-grouped
    conv_body(p.Wqkv + (long long)layer * 3145728,
              p.Wqh + (long long)layer * 3145728,
              p.Wql + (long long)layer * 3145728, 256, 768, 768, 196608LL,
              r % 96, r / 96, smem);
  } else if (r < 512) {
    int v = r - 384;  // Wo: K=4096 (64 k-blk), N=256 (2 n-blk)
    conv_body(p.Wo + (long long)layer * 1048576,
              p.Woh + (long long)layer * 1048576,
              p.Wol + (long long)layer * 1048576, 4096, 256, 1 << 30, 0LL,
              v % 2, v / 2, smem);
  } else if (r < 544) {
    int v = r - 512;  // Wm1: K=256 (4 k-blk), N=1024 (8 n-blk)
    conv_body(p.Wm1 + (long long)layer * 262144,
              p.W1h + (long long)layer * 262144,
              p.W1l + (long long)layer * 262144, 256, 1024, 1 << 30, 0LL,
              v % 8, v / 8, smem);
  } else {
    int v = r - 544;  // Wm2: K=1024 (16 k-blk), N=256 (2 n-blk)
    conv_body(p.Wm2 + (long long)layer * 262144,
              p.W2h + (long long)layer * 262144,
              p.W2l + (long long)layer * 262144, 1024, 256, 1 << 30, 0LL,
              v % 2, v / 2, smem);
  }
}

// -------- MFMA bf16x3 GEMM (fp32-quality), 128x128 tile, m97 structure ----
__global__ __launch_bounds__(256) void gemm_x3(
    const short* __restrict__ Ah, const short* __restrict__ Al,
    const short* __restrict__ Bh, const short* __restrict__ Bl, int M, int N,
    int K, int kchunk, const float* __restrict__ bias,
    float* __restrict__ out32, float* __restrict__ P) {
  __shared__ short Ash[128 * 64];
  __shared__ short Asl[128 * 64];
  __shared__ short Bsh[128 * 64];
  __shared__ short Bsl[128 * 64];
  const int tid = threadIdx.x;
  const int w = tid >> 6, l = tid & 63;
  const int col0 = blockIdx.x * 128;
  const int row0 = blockIdx.y * 128;
  const int kbeg = blockIdx.z * kchunk;
  const int kend = kbeg + kchunk;
  const int wm = w >> 1, wn = w & 1;  // 2x2 waves of 64x64

  f32x4 acc[4][4];
#pragma unroll
  for (int i = 0; i < 4; ++i)
#pragma unroll
    for (int j = 0; j < 4; ++j) acc[i][j] = (f32x4)(0.f);

  const int srow = l >> 3;  // row within 8-row chunk
  const int sslot = l & 7;  // 16B slot

#define STAGE4(dst, src, rbase)                                            \
  {                                                                        \
    _Pragma("unroll") for (int i = 0; i < 4; ++i) {                        \
      int r = (w * 4 + i) * 8 + srow;                                      \
      const char* gp =                                                     \
          (const char*)(src + (size_t)(rbase + r) * K + k0) + sslot * 16;  \
      short* lp = dst + (w * 4 + i) * 512;                                 \
      __builtin_amdgcn_global_load_lds(                                    \
          (const __attribute__((address_space(1))) unsigned int*)gp,       \
          (__attribute__((address_space(3))) unsigned int*)lp, 16, 0, 0);  \
    }                                                                      \
  }

  for (int k0 = kbeg; k0 < kend; k0 += 64) {
    __syncthreads();
    STAGE4(Ash, Ah, row0)
    STAGE4(Asl, Al, row0)
    STAGE4(Bsh, Bh, col0)
    STAGE4(Bsl, Bl, col0)
    __syncthreads();
#pragma unroll
    for (int kc = 0; kc < 2; ++kc) {
      short8 ah[4], al[4], bh[4], bl[4];
#pragma unroll
      for (int mi = 0; mi < 4; ++mi) {
        int row = wm * 64 + mi * 16 + (l & 15);
        int slot = (kc * 4 + (l >> 4)) ^ (row & 7);
        ah[mi] = *(const short8*)&Ash[row * 64 + slot * 8];
        al[mi] = *(const short8*)&Asl[row * 64 + slot * 8];
      }
#pragma unroll
      for (int ni = 0; ni < 4; ++ni) {
        int row = wn * 64 + ni * 16 + (l & 15);
        int slot = (kc * 4 + (l >> 4)) ^ (row & 7);
        bh[ni] = *(const short8*)&Bsh[row * 64 + slot * 8];
        bl[ni] = *(const short8*)&Bsl[row * 64 + slot * 8];
      }
#pragma unroll
      for (int mi = 0; mi < 4; ++mi)
#pragma unroll
        for (int ni = 0; ni < 4; ++ni) {
          acc[mi][ni] = __builtin_amdgcn_mfma_f32_16x16x32_bf16(
              ah[mi], bh[ni], acc[mi][ni], 0, 0, 0);
          acc[mi][ni] = __builtin_amdgcn_mfma_f32_16x16x32_bf16(
              ah[mi], bl[ni], acc[mi][ni], 0, 0, 0);
          acc[mi][ni] = __builtin_amdgcn_mfma_f32_16x16x32_bf16(
              al[mi], bh[ni], acc[mi][ni], 0, 0, 0);
        }
    }
  }
#undef STAGE4

#pragma unroll
  for (int mi = 0; mi < 4; ++mi) {
#pragma unroll
    for (int ni = 0; ni < 4; ++ni) {
      int row = row0 + wm * 64 + mi * 16 + (l >> 4) * 4;
      int col = col0 + wn * 64 + ni * 16 + (l & 15);
      if (out32) {
        float bc = bias ? bias[col] : 0.f;
#pragma unroll
        for (int r = 0; r < 4; ++r)
          if (row + r < M)
            out32[(size_t)(row + r) * N + col] = acc[mi][ni][r] + bc;
      } else {
        float* Pz = P + (size_t)blockIdx.z * M * N;
#pragma unroll
        for (int r = 0; r < 4; ++r)
          if (row + r < M) Pz[(size_t)(row + r) * N + col] = acc[mi][ni][r];
      }
    }
  }
}

// ------ split-K reduce + bias + act + residual (+ LN); NSPLIT unrolled ----
template <int NSPLIT>
__global__ __launch_bounds__(256) void epilogue_kernel(
    const float* __restrict__ P, int M, int N, const float* __restrict__ bias,
    const float* __restrict__ res, float* __restrict__ out32,
    short* __restrict__ o16h, short* __restrict__ o16l, int act,
    const float* __restrict__ g, const float* __restrict__ bln,
    short* __restrict__ z16h, short* __restrict__ z16l) {
  __shared__ float sb[4];
  int r = blockIdx.x;
  float myval = 0.f;
  for (int c = threadIdx.x; c < N; c += 256) {
    const float* pp = P + (long long)r * N + c;
    float acc = 0.f;
#pragma unroll
    for (int s = 0; s < NSPLIT; ++s) acc += pp[(long long)s * M * N];
    acc += bias[c];
    if (act) acc = gelu_f(acc);
    if (res) acc += res[(long long)r * N + c];
    if (out32) out32[(long long)r * N + c] = acc;
    if (o16h) {
      short h, L;
      split2(acc, h, L);
      o16h[(long long)r * N + swz(c, r)] = h;
      o16l[(long long)r * N + swz(c, r)] = L;
    }
    myval = acc;
  }
  if (z16h) {  // N==256 only
    float mean = block_sum_256(myval, sb) * (1.f / 256.f);
    float dv = myval - mean;
    float var = block_sum_256(dv * dv, sb) * (1.f / 256.f);
    float z = dv * rsqrtf(var + 1e-5f) * g[threadIdx.x] + bln[threadIdx.x];
    short h, L;
    split2(z, h, L);
    z16h[r * 256 + swz((int)threadIdx.x, r)] = h;
    z16l[r * 256 + swz((int)threadIdx.x, r)] = L;
  }
}

// ------- attention (fp32 qkv in, hi/lo bf16 out), 17 q-rows per block -----
#define AROWS 17
__global__ __launch_bounds__(256) void attn_kernel(const float* __restrict__ qkv,
                                                   short* __restrict__ Oh,
                                                   short* __restrict__ Ol) {
  __shared__ float qs[AROWS + 1][256];
  __shared__ float Ks[68][68];
  __shared__ float ps[AROWS][66];
  const int tid = threadIdx.x;
  const int s0 = blockIdx.x * AROWS;
  const int bh = blockIdx.y;
  const int b = bh >> 4, h = bh & 15;
  const long long base = (long long)(b * 65) * 12288 + h * 768;

#pragma unroll
  for (int i = 0; i < AROWS; ++i) {
    int s = s0 + i;
    qs[i][tid] = (s < 65) ? qkv[base + (long long)s * 12288 + tid] : 0.f;
  }

  const int up = tid / 17, tg = tid % 17;
  const int i0 = up * 2, t0 = tg * 4;
  const bool uval = (tid < 153);
  float acc[2][4] = {};
  for (int dc = 0; dc < 256; dc += 64) {
    __syncthreads();
    for (int idx = tid; idx < 65 * 64; idx += 256) {
      int t = idx >> 6, dd = idx & 63;
      Ks[t][dd] = qkv[base + (long long)t * 12288 + 256 + dc + dd];
    }
    __syncthreads();
    if (uval) {
#pragma unroll
      for (int d4 = 0; d4 < 64; d4 += 4) {
        float4 qa = *(const float4*)&qs[i0][dc + d4];
        float4 qb = *(const float4*)&qs[i0 + 1][dc + d4];
#pragma unroll
        for (int c = 0; c < 4; ++c) {
          float4 kv = *(const float4*)&Ks[t0 + c][d4];
          acc[0][c] += qa.x * kv.x + qa.y * kv.y + qa.z * kv.z + qa.w * kv.w;
          acc[1][c] += qb.x * kv.x + qb.y * kv.y + qb.z * kv.z + qb.w * kv.w;
        }
      }
    }
  }
  if (uval) {
#pragma unroll
    for (int ii = 0; ii < 2; ++ii) {
      int i = i0 + ii;
      if (i < AROWS && (s0 + i) < 65) {
#pragma unroll
        for (int c = 0; c < 4; ++c) {
          int t = t0 + c;
          if (t < 65) ps[i][t] = acc[ii][c] * 0.25f;
        }
      }
    }
  }
  __syncthreads();

  if (tid < AROWS && (s0 + tid) < 65) {
    float* row = ps[tid];
    float m = row[0];
    for (int t = 1; t < 65; ++t) m = fmaxf(m, row[t]);
    float sum = 0.f;
    for (int t = 0; t < 65; ++t) {
      float e = expf(row[t] - m);
      row[t] = e;
      sum += e;
    }
    float inv = 1.f / sum;
    for (int t = 0; t < 65; ++t) row[t] *= inv;
  }
  __syncthreads();

  float oacc[AROWS];
#pragma unroll
  for (int i = 0; i < AROWS; ++i) oacc[i] = 0.f;
  const float* vp = qkv + base + 512 + tid;
  for (int t = 0; t < 65; ++t) {
    float vtd = vp[(long long)t * 12288];
#pragma unroll
    for (int i = 0; i < AROWS; ++i) oacc[i] += ps[i][t] * vtd;
  }
#pragma unroll
  for (int i = 0; i < AROWS; ++i) {
    int s = s0 + i;
    if (s < 65) {
      int row = b * 65 + s;
      int col = h * 256 + ((tid & ~63) | ((tid & 63) ^ ((row & 7) << 3)));
      short hh, LL;
      split2(oacc[i], hh, LL);
      Oh[(long long)row * 4096 + col] = hh;
      Ol[(long long)row * 4096 + col] = LL;
    }
  }
}

// ---------------- head GEMMs (fp32, tiny) ----------------
template <int KS>
__global__ __launch_bounds__(256) void head_gemm2(
    const float* __restrict__ A, int lda, const float* __restrict__ B,
    const float* __restrict__ bias, float* __restrict__ C, int N, int K,
    int act) {
  constexpr int COLS = 256 / KS;
  __shared__ float red[KS][COLS];
  const int lane = threadIdx.x % COLS;
  const int ks = threadIdx.x / COLS;
  const int c = blockIdx.x * COLS + lane;
  const int r = blockIdx.y;
  const float* a = A + (long long)r * lda;
  float acc = 0.f;
  const int kc = K / KS;
  if (c < N) {
    const float* ap = a + ks * kc;
    const float* bp = B + (long long)(ks * kc) * N + c;
#pragma unroll 8
    for (int k = 0; k < kc; ++k) acc += ap[k] * bp[(long long)k * N];
  }
  red[ks][lane] = acc;
  __syncthreads();
  if (ks == 0 && c < N) {
    float v = bias[c];
#pragma unroll
    for (int s = 0; s < KS; ++s) v += red[s][lane];
    if (act) v = gelu_f(v);
    C[(long long)r * N + c] = v;
  }
}

extern "C" void kernel_launch(void* const* d_in, const int* in_sizes, int n_in,
                              void* d_out, int out_size, void* d_ws,
                              size_t ws_size, hipStream_t stream) {
  const float* x = (const float*)d_in[0];
  const float* conv_w = (const float*)d_in[1];
  const float* conv_b = (const float*)d_in[2];
  const float* cls = (const float*)d_in[3];
  const float* pos = (const float*)d_in[4];
  const float* Wqkv = (const float*)d_in[5];
  const float* bqkv = (const float*)d_in[6];
  const float* Wo = (const float*)d_in[7];
  const float* bo = (const float*)d_in[8];
  const float* ln1g = (const float*)d_in[9];
  const float* ln1b = (const float*)d_in[10];
  const float* ln2g = (const float*)d_in[11];
  const float* ln2b = (const float*)d_in[12];
  const float* Wm1 = (const float*)d_in[13];
  const float* bm1 = (const float*)d_in[14];
  const float* Wm2 = (const float*)d_in[15];
  const float* bm2 = (const float*)d_in[16];
  const float* Wh1 = (const float*)d_in[17];
  const float* bh1 = (const float*)d_in[18];
  const float* Wh2 = (const float*)d_in[19];
  const float* bh2 = (const float*)d_in[20];
  const float* Wh3 = (const float*)d_in[21];
  const float* bh3 = (const float*)d_in[22];
  float* out = (float*)d_out;

  // ---- workspace map (float units; identical to round-5 proven map) ----
  float* ws = (float*)d_ws;
  float* tok = ws;
  float* y1 = ws + 163840;
  float* Pb = ws + 327680;
  float* qkvf = ws + 2457600;
  short* zh = (short*)(ws + 8847360);
  short* zl = (short*)(ws + 8929280);
  short* Oh = (short*)(ws + 9011200);
  short* Ol = (short*)(ws + 10321920);
  short* h1h = (short*)(ws + 11632640);
  short* h1l = (short*)(ws + 11960320);
  float* hh1 = ws + 12288000;
  float* hh2 = ws + 12296192;
  short* Wqh = (short*)(ws + 12298240);
  short* Wql = (short*)(ws + 50046976);
  short* Woh = (short*)(ws + 87795712);
  short* Wol_ = (short*)(ws + 100378624);
  short* W1h = (short*)(ws + 112961536);
  short* W1l = (short*)(ws + 116107264);
  short* W2h = (short*)(ws + 119252992);
  short* W2l = (short*)(ws + 122398720);

  const int M = 520;

  // one prep dispatch: embed+LN1 (520 blocks) + all weight converts
  PrepArgs p;
  p.x = x; p.cw = conv_w; p.cb = conv_b; p.cls = cls; p.pos = pos;
  p.ln1g = ln1g; p.ln1b = ln1b;
  p.tok = tok; p.zh = zh; p.zl = zl;
  p.Wqkv = Wqkv; p.Wo = Wo; p.Wm1 = Wm1; p.Wm2 = Wm2;
  p.Wqh = Wqh; p.Wql = Wql; p.Woh = Woh; p.Wol = Wol_;
  p.W1h = W1h; p.W1l = W1l; p.W2h = W2h; p.W2l = W2l;
  prep_kernel<<<520 + 24 * 576, 256, 0, stream>>>(p);

  for (int l = 0; l < 24; ++l) {
    const short* Wqhl = Wqh + (long long)l * 3145728;
    const short* Wqll = Wql + (long long)l * 3145728;
    const short* Wohl = Woh + (long long)l * 1048576;
    const short* Woll = Wol_ + (long long)l * 1048576;
    const short* W1hl = W1h + (long long)l * 262144;
    const short* W1ll = W1l + (long long)l * 262144;
    const short* W2hl = W2h + (long long)l * 262144;
    const short* W2ll = W2l + (long long)l * 262144;
    const float* bq = bqkv + l * 12288;
    const float* bol = bo + l * 256;
    const float* b1 = bm1 + l * 1024;
    const float* b2 = bm2 + l * 256;

    // QKV: z @ Wq -> qkvf fp32 (+bias)
    gemm_x3<<<dim3(96, 5, 1), 256, 0, stream>>>(zh, zl, Wqhl, Wqll, M, 12288,
                                                256, 256, bq, qkvf, nullptr);

    attn_kernel<<<dim3(4, 128), 256, 0, stream>>>(qkvf, Oh, Ol);

    // Wo: O(520x4096) @ Wo'(256x4096), split-K 16
    gemm_x3<<<dim3(2, 5, 16), 256, 0, stream>>>(Oh, Ol, Wohl, Woll, M, 256,
                                                4096, 256, nullptr, nullptr,
                                                Pb);
    epilogue_kernel<16><<<520, 256, 0, stream>>>(
        Pb, M, 256, bol, tok, y1, nullptr, nullptr, 0, ln2g + l * 256,
        ln2b + l * 256, zh, zl);

    // MLP1: z @ Wm1'(1024x256), split-K 4, gelu -> h1 hi/lo
    gemm_x3<<<dim3(8, 5, 4), 256, 0, stream>>>(zh, zl, W1hl, W1ll, M, 1024,
                                               256, 64, nullptr, nullptr, Pb);
    epilogue_kernel<4><<<520, 256, 0, stream>>>(Pb, M, 1024, b1, nullptr,
                                                nullptr, h1h, h1l, 1, nullptr,
                                                nullptr, nullptr, nullptr);

    // MLP2: h1 @ Wm2'(256x1024), split-K 16, gelu, +y1 -> tok
    gemm_x3<<<dim3(2, 5, 16), 256, 0, stream>>>(h1h, h1l, W2hl, W2ll, M, 256,
                                                1024, 64, nullptr, nullptr,
                                                Pb);
    const float* ng = (l < 23) ? ln1g + (l + 1) * 256 : nullptr;
    const float* nb = (l < 23) ? ln1b + (l + 1) * 256 : nullptr;
    short* nzh = (l < 23) ? zh : nullptr;
    short* nzl = (l < 23) ? zl : nullptr;
    epilogue_kernel<16><<<520, 256, 0, stream>>>(Pb, M, 256, b2, y1, tok,
                                                 nullptr, nullptr, 1, ng, nb,
                                                 nzh, nzl);
  }

  head_gemm2<4><<<dim3(16, 8), 256, 0, stream>>>(tok, 16640, Wh1, bh1, hh1,
                                                 1024, 256, 1);
  head_gemm2<8><<<dim3(8, 8), 256, 0, stream>>>(hh1, 1024, Wh2, bh2, hh2, 256,
                                                1024, 1);
  head_gemm2<4><<<dim3(16, 8), 256, 0, stream>>>(hh2, 256, Wh3, bh3, out, 1000,
                                                 256, 0);
}